// Round 1
// baseline (803.032 us; speedup 1.0000x reference)
//
#include <hip/hip_runtime.h>
#include <stdint.h>

// ---- problem constants ----
#define B_  4
#define T_  2048
#define D_  1024
#define H_  16
#define HD_ 64

typedef short s16x8 __attribute__((ext_vector_type(8)));
typedef float f32x4 __attribute__((ext_vector_type(4)));

__device__ __forceinline__ unsigned short f2bf(float f) {
    union { float f; unsigned int u; } v; v.f = f;
    unsigned int r = v.u + 0x7fffu + ((v.u >> 16) & 1u);   // RNE
    return (unsigned short)(r >> 16);
}

__device__ __forceinline__ void async16(const void* g, void* l) {
    __builtin_amdgcn_global_load_lds(
        (const __attribute__((address_space(1))) unsigned int*)g,
        (__attribute__((address_space(3))) unsigned int*)l, 16, 0, 0);
}

// ---------------- cast x (fp32 -> bf16), 4 elems/thread ----------------
__global__ void cast_bf16_kernel(const float* __restrict__ in,
                                 unsigned short* __restrict__ out, int n4) {
    int i = blockIdx.x * 256 + threadIdx.x;
    if (i < n4) {
        float4 v = ((const float4*)in)[i];
        ushort4 o;
        o.x = f2bf(v.x); o.y = f2bf(v.y); o.z = f2bf(v.z); o.w = f2bf(v.w);
        ((ushort4*)out)[i] = o;
    }
}

// ------------- transpose+cast: W[K,N] fp32 -> Wt[N,K] bf16 -------------
// block(32,8), grid(N/32, K/32)
__global__ void transpose_cast_kernel(const float* __restrict__ W,
                                      unsigned short* __restrict__ Wt,
                                      int K, int N) {
    __shared__ float t[32][33];
    const int bx = blockIdx.x * 32;   // n
    const int by = blockIdx.y * 32;   // k
    const int tx = threadIdx.x, ty = threadIdx.y;
    #pragma unroll
    for (int j = 0; j < 32; j += 8)
        t[ty + j][tx] = W[(size_t)(by + ty + j) * N + bx + tx];
    __syncthreads();
    #pragma unroll
    for (int j = 0; j < 32; j += 8)
        Wt[(size_t)(bx + ty + j) * K + by + tx] = f2bf(t[tx][ty + j]);
}

// ---------------- bf16 MFMA GEMM: C = A[M,K] @ Bt[N,K]^T + bias --------
// m97 structure: 128x128 tile, BK=32, global_load_lds(16), 4 waves 2x2.
// MODE 0: Cf[m*N+n] = acc + bias[n]  (fp32)
// MODE 1: QKV scatter: n -> (s,h,d); Q,K -> [B,H,T,64] bf16; V -> [B,H,64,T] bf16
template <int MODE>
__global__ __launch_bounds__(256)
void gemm_bt_kernel(const unsigned short* __restrict__ A,
                    const unsigned short* __restrict__ Bt,
                    const float* __restrict__ bias,
                    float* __restrict__ Cf,
                    unsigned short* __restrict__ Qo,
                    unsigned short* __restrict__ Ko,
                    unsigned short* __restrict__ Vo,
                    int M, int N, int K) {
    __shared__ __align__(16) unsigned short As[128 * 32];
    __shared__ __align__(16) unsigned short Bs[128 * 32];
    const int tid = threadIdx.x;
    const int w = tid >> 6, lane = tid & 63;
    const int laneN = lane & 15, quad = lane >> 4;
    const int rm0 = blockIdx.y * 128, rn0 = blockIdx.x * 128;
    const int wr = (w >> 1) * 64, wc = (w & 1) * 64;

    f32x4 acc[4][4] = {};

    for (int kk = 0; kk < K; kk += 32) {
        #pragma unroll
        for (int i = 0; i < 2; ++i) {
            const int c = (w * 2 + i) * 64 + lane;   // 0..511 chunk id
            const int row = c >> 2, k2 = c & 3;
            async16(A  + (size_t)(rm0 + row) * K + kk + k2 * 8, (char*)As + (size_t)c * 16);
            async16(Bt + (size_t)(rn0 + row) * K + kk + k2 * 8, (char*)Bs + (size_t)c * 16);
        }
        __syncthreads();
        s16x8 av[4], bv[4];
        #pragma unroll
        for (int ms = 0; ms < 4; ++ms)
            av[ms] = *(const s16x8*)&As[(wr + ms * 16 + laneN) * 32 + quad * 8];
        #pragma unroll
        for (int ns = 0; ns < 4; ++ns)
            bv[ns] = *(const s16x8*)&Bs[(wc + ns * 16 + laneN) * 32 + quad * 8];
        #pragma unroll
        for (int ms = 0; ms < 4; ++ms)
            #pragma unroll
            for (int ns = 0; ns < 4; ++ns)
                acc[ms][ns] = __builtin_amdgcn_mfma_f32_16x16x32_bf16(
                    av[ms], bv[ns], acc[ms][ns], 0, 0, 0);
        __syncthreads();
    }

    if (MODE == 0) {
        #pragma unroll
        for (int ms = 0; ms < 4; ++ms) {
            const int gm0 = rm0 + wr + ms * 16 + quad * 4;
            #pragma unroll
            for (int ns = 0; ns < 4; ++ns) {
                const int gn = rn0 + wc + ns * 16 + laneN;
                const float bb = bias[gn];
                #pragma unroll
                for (int r = 0; r < 4; ++r)
                    Cf[(size_t)(gm0 + r) * N + gn] = acc[ms][ns][r] + bb;
            }
        }
    } else {
        #pragma unroll
        for (int ms = 0; ms < 4; ++ms) {
            const int gm0 = rm0 + wr + ms * 16 + quad * 4;
            #pragma unroll
            for (int ns = 0; ns < 4; ++ns) {
                const int gn = rn0 + wc + ns * 16 + laneN;
                const float bb = bias[gn];
                const int s = gn >> 10, rr = gn & 1023, hh = rr >> 6, dd = rr & 63;
                #pragma unroll
                for (int r = 0; r < 4; ++r) {
                    const int gm = gm0 + r;
                    const int bidx = gm >> 11, t = gm & (T_ - 1);
                    const unsigned short val = f2bf(acc[ms][ns][r] + bb);
                    const int bh = bidx * H_ + hh;
                    if (s == 0)      Qo[((size_t)bh * T_ + t) * HD_ + dd] = val;
                    else if (s == 1) Ko[((size_t)bh * T_ + t) * HD_ + dd] = val;
                    else             Vo[((size_t)bh * HD_ + dd) * T_ + t] = val;
                }
            }
        }
    }
}

// ---------------- flash attention ----------------
// grid(T/64, B*H), 256 thr. Wave w: 16 Q-rows. Key tiles of 64.
// Q,K: [B*H, T, 64] bf16 ; VT: [B*H, 64, T] bf16 ; Out: [B*T, 1024] bf16.
__global__ __launch_bounds__(256)
void attn_kernel(const unsigned short* __restrict__ Q,
                 const unsigned short* __restrict__ Kt,
                 const unsigned short* __restrict__ VT,
                 const int* __restrict__ mask,
                 unsigned short* __restrict__ Out) {
    // padded stride 72 (-> 2-way LDS conflicts only, free per m136)
    __shared__ __align__(16) unsigned short plds[4][16][72];
    const int tid = threadIdx.x;
    const int w = tid >> 6, lane = tid & 63;
    const int laneN = lane & 15, quad = lane >> 4;
    const int bh = blockIdx.y;
    const int b = bh >> 4, h = bh & 15;
    const int qbase = blockIdx.x * 64 + w * 16;

    // A-operand layout: m = lane&15, k = quad*8+j
    const size_t qoff = ((size_t)bh * T_ + qbase) * HD_;
    const s16x8 qf0 = *(const s16x8*)&Q[qoff + (size_t)laneN * HD_ + quad * 8];
    const s16x8 qf1 = *(const s16x8*)&Q[qoff + (size_t)laneN * HD_ + 32 + quad * 8];

    float mi[4], li[4];
    f32x4 O[4] = {};
    #pragma unroll
    for (int r = 0; r < 4; ++r) { mi[r] = -1e30f; li[r] = 0.f; }

    for (int kt = 0; kt < T_ / 64; ++kt) {
        const int kbase = kt * 64;
        f32x4 S[4];
        // S = Q @ K^T : B-operand n = key (lane&15), k = d (quad*8+j)
        #pragma unroll
        for (int ns = 0; ns < 4; ++ns) {
            const size_t koff = ((size_t)bh * T_ + kbase + ns * 16 + laneN) * HD_;
            f32x4 s = {};
            s = __builtin_amdgcn_mfma_f32_16x16x32_bf16(
                qf0, *(const s16x8*)&Kt[koff + quad * 8], s, 0, 0, 0);
            s = __builtin_amdgcn_mfma_f32_16x16x32_bf16(
                qf1, *(const s16x8*)&Kt[koff + 32 + quad * 8], s, 0, 0, 0);
            S[ns] = s;
        }
        // scale + mask (per key column)
        #pragma unroll
        for (int ns = 0; ns < 4; ++ns) {
            const int tk = kbase + ns * 16 + laneN;
            const bool keep = mask[b * T_ + tk] != 0;
            #pragma unroll
            for (int r = 0; r < 4; ++r)
                S[ns][r] = keep ? S[ns][r] * 0.125f : -1e9f;
        }
        // online softmax: stats for row quad*4+r live in 16-lane groups
        float rmax[4];
        #pragma unroll
        for (int r = 0; r < 4; ++r)
            rmax[r] = fmaxf(fmaxf(S[0][r], S[1][r]), fmaxf(S[2][r], S[3][r]));
        #pragma unroll
        for (int off = 1; off <= 8; off <<= 1)
            #pragma unroll
            for (int r = 0; r < 4; ++r)
                rmax[r] = fmaxf(rmax[r], __shfl_xor(rmax[r], off));
        float alpha[4], rsum[4];
        #pragma unroll
        for (int r = 0; r < 4; ++r) {
            const float mnew = fmaxf(mi[r], rmax[r]);
            alpha[r] = __expf(mi[r] - mnew);
            mi[r] = mnew;
            rsum[r] = 0.f;
        }
        #pragma unroll
        for (int ns = 0; ns < 4; ++ns)
            #pragma unroll
            for (int r = 0; r < 4; ++r) {
                const float p = __expf(S[ns][r] - mi[r]);
                S[ns][r] = p;
                rsum[r] += p;
            }
        #pragma unroll
        for (int off = 1; off <= 8; off <<= 1)
            #pragma unroll
            for (int r = 0; r < 4; ++r)
                rsum[r] += __shfl_xor(rsum[r], off);
        #pragma unroll
        for (int r = 0; r < 4; ++r)
            li[r] = li[r] * alpha[r] + rsum[r];
        #pragma unroll
        for (int ds = 0; ds < 4; ++ds)
            #pragma unroll
            for (int r = 0; r < 4; ++r)
                O[ds][r] *= alpha[r];
        // P: C-layout -> A-layout via LDS (wave-private region)
        #pragma unroll
        for (int ns = 0; ns < 4; ++ns)
            #pragma unroll
            for (int r = 0; r < 4; ++r)
                plds[w][quad * 4 + r][ns * 16 + laneN] = f2bf(S[ns][r]);
        __syncthreads();
        const s16x8 pf0 = *(const s16x8*)&plds[w][laneN][quad * 8];
        const s16x8 pf1 = *(const s16x8*)&plds[w][laneN][32 + quad * 8];
        // O += P @ V : B-operand n = d (lane&15), k = key (quad*8+j) from VT
        #pragma unroll
        for (int ds = 0; ds < 4; ++ds) {
            const size_t voff = ((size_t)bh * HD_ + ds * 16 + laneN) * T_ + kbase;
            O[ds] = __builtin_amdgcn_mfma_f32_16x16x32_bf16(
                pf0, *(const s16x8*)&VT[voff + quad * 8], O[ds], 0, 0, 0);
            O[ds] = __builtin_amdgcn_mfma_f32_16x16x32_bf16(
                pf1, *(const s16x8*)&VT[voff + 32 + quad * 8], O[ds], 0, 0, 0);
        }
    }
    // epilogue: Out[b,t, h*64 + d] bf16
    #pragma unroll
    for (int ds = 0; ds < 4; ++ds)
        #pragma unroll
        for (int r = 0; r < 4; ++r) {
            const int tq = qbase + quad * 4 + r;
            const float v = O[ds][r] / li[r];
            Out[((size_t)(b * T_ + tq)) * D_ + h * HD_ + ds * 16 + laneN] = f2bf(v);
        }
}

extern "C" void kernel_launch(void* const* d_in, const int* in_sizes, int n_in,
                              void* d_out, int out_size, void* d_ws, size_t ws_size,
                              hipStream_t stream) {
    const float* x     = (const float*)d_in[0];
    const int*   mask  = (const int*)d_in[1];
    const float* W_qkv = (const float*)d_in[2];
    const float* b_qkv = (const float*)d_in[3];
    const float* W_out = (const float*)d_in[4];
    const float* b_out = (const float*)d_in[5];
    float* out = (float*)d_out;

    unsigned short* ws = (unsigned short*)d_ws;
    const size_t NX = (size_t)B_ * T_ * D_;          // 8388608
    unsigned short* xb  = ws;                        // x bf16; reused for attn out
    unsigned short* Qb  = xb + NX;
    unsigned short* Kb  = Qb + NX;
    unsigned short* Vtb = Kb + NX;
    unsigned short* Wqt = Vtb + NX;                  // [3D, D]
    unsigned short* Wot = Wqt + (size_t)3 * D_ * D_; // [D, D]
    unsigned short* attn = xb;                       // alias: xb dead after GEMM1

    cast_bf16_kernel<<<(int)(NX / 4 + 255) / 256, 256, 0, stream>>>(x, xb, (int)(NX / 4));
    {
        dim3 blk(32, 8), grd(3 * D_ / 32, D_ / 32);
        transpose_cast_kernel<<<grd, blk, 0, stream>>>(W_qkv, Wqt, D_, 3 * D_);
    }
    {
        dim3 blk(32, 8), grd(D_ / 32, D_ / 32);
        transpose_cast_kernel<<<grd, blk, 0, stream>>>(W_out, Wot, D_, D_);
    }
    gemm_bt_kernel<1><<<dim3(3 * D_ / 128, B_ * T_ / 128), 256, 0, stream>>>(
        xb, Wqt, b_qkv, nullptr, Qb, Kb, Vtb, B_ * T_, 3 * D_, D_);
    attn_kernel<<<dim3(T_ / 64, B_ * H_), 256, 0, stream>>>(Qb, Kb, Vtb, mask, attn);
    gemm_bt_kernel<0><<<dim3(D_ / 128, B_ * T_ / 128), 256, 0, stream>>>(
        attn, Wot, b_out, out, nullptr, nullptr, nullptr, B_ * T_, D_, D_);
}

// Round 2
// 583.982 us; speedup vs baseline: 1.3751x; 1.3751x over previous
//
#include <hip/hip_runtime.h>
#include <hip/hip_bf16.h>
#include <stdint.h>

// ---- problem constants ----
#define B_  4
#define T_  2048
#define D_  1024
#define H_  16
#define HD_ 64

typedef short s16x8 __attribute__((ext_vector_type(8)));
typedef short s16x4 __attribute__((ext_vector_type(4)));
typedef float f32x4 __attribute__((ext_vector_type(4)));

#define MFMA32(a, b, c) __builtin_amdgcn_mfma_f32_16x16x32_bf16(a, b, c, 0, 0, 0)
#define MFMA16(a, b, c) __builtin_amdgcn_mfma_f32_16x16x16bf16_1k(a, b, c, 0, 0, 0)

__device__ __forceinline__ unsigned short f2bf(float f) {
    union { float f; unsigned int u; } v; v.f = f;
    unsigned int r = v.u + 0x7fffu + ((v.u >> 16) & 1u);   // RNE
    return (unsigned short)(r >> 16);
}

__device__ __forceinline__ unsigned int pkbf(float a, float b) {
    __hip_bfloat162 h = __float22bfloat162_rn(float2{a, b});  // v_cvt_pk_bf16_f32
    union { __hip_bfloat162 h; unsigned int u; } v; v.h = h;
    return v.u;
}

__device__ __forceinline__ void async16(const void* g, void* l) {
    __builtin_amdgcn_global_load_lds(
        (const __attribute__((address_space(1))) unsigned int*)g,
        (__attribute__((address_space(3))) unsigned int*)l, 16, 0, 0);
}

// ---------------- cast x (fp32 -> bf16), 4 elems/thread ----------------
__global__ void cast_bf16_kernel(const float* __restrict__ in,
                                 unsigned short* __restrict__ out, int n4) {
    int i = blockIdx.x * 256 + threadIdx.x;
    if (i < n4) {
        float4 v = ((const float4*)in)[i];
        ushort4 o;
        o.x = f2bf(v.x); o.y = f2bf(v.y); o.z = f2bf(v.z); o.w = f2bf(v.w);
        ((ushort4*)out)[i] = o;
    }
}

// ------------- transpose+cast: W[K,N] fp32 -> Wt[N,K] bf16 -------------
__global__ void transpose_cast_kernel(const float* __restrict__ W,
                                      unsigned short* __restrict__ Wt,
                                      int K, int N) {
    __shared__ float t[32][33];
    const int bx = blockIdx.x * 32;   // n
    const int by = blockIdx.y * 32;   // k
    const int tx = threadIdx.x, ty = threadIdx.y;
    #pragma unroll
    for (int j = 0; j < 32; j += 8)
        t[ty + j][tx] = W[(size_t)(by + ty + j) * N + bx + tx];
    __syncthreads();
    #pragma unroll
    for (int j = 0; j < 32; j += 8)
        Wt[(size_t)(bx + ty + j) * K + by + tx] = f2bf(t[tx][ty + j]);
}

// ---------------- bf16 MFMA GEMM: C = A[M,K] @ Bt[N,K]^T + bias --------
template <int MODE>
__global__ __launch_bounds__(256)
void gemm_bt_kernel(const unsigned short* __restrict__ A,
                    const unsigned short* __restrict__ Bt,
                    const float* __restrict__ bias,
                    float* __restrict__ Cf,
                    unsigned short* __restrict__ Qo,
                    unsigned short* __restrict__ Ko,
                    unsigned short* __restrict__ Vo,
                    int M, int N, int K) {
    __shared__ __align__(16) unsigned short As[128 * 32];
    __shared__ __align__(16) unsigned short Bs[128 * 32];
    const int tid = threadIdx.x;
    const int w = tid >> 6, lane = tid & 63;
    const int laneN = lane & 15, quad = lane >> 4;
    const int rm0 = blockIdx.y * 128, rn0 = blockIdx.x * 128;
    const int wr = (w >> 1) * 64, wc = (w & 1) * 64;

    f32x4 acc[4][4] = {};

    for (int kk = 0; kk < K; kk += 32) {
        #pragma unroll
        for (int i = 0; i < 2; ++i) {
            const int c = (w * 2 + i) * 64 + lane;   // 0..511 chunk id
            const int row = c >> 2, k2 = c & 3;
            async16(A  + (size_t)(rm0 + row) * K + kk + k2 * 8, (char*)As + (size_t)c * 16);
            async16(Bt + (size_t)(rn0 + row) * K + kk + k2 * 8, (char*)Bs + (size_t)c * 16);
        }
        __syncthreads();
        s16x8 av[4], bv[4];
        #pragma unroll
        for (int ms = 0; ms < 4; ++ms)
            av[ms] = *(const s16x8*)&As[(wr + ms * 16 + laneN) * 32 + quad * 8];
        #pragma unroll
        for (int ns = 0; ns < 4; ++ns)
            bv[ns] = *(const s16x8*)&Bs[(wc + ns * 16 + laneN) * 32 + quad * 8];
        #pragma unroll
        for (int ms = 0; ms < 4; ++ms)
            #pragma unroll
            for (int ns = 0; ns < 4; ++ns)
                acc[ms][ns] = MFMA32(av[ms], bv[ns], acc[ms][ns]);
        __syncthreads();
    }

    if (MODE == 0) {
        #pragma unroll
        for (int ms = 0; ms < 4; ++ms) {
            const int gm0 = rm0 + wr + ms * 16 + quad * 4;
            #pragma unroll
            for (int ns = 0; ns < 4; ++ns) {
                const int gn = rn0 + wc + ns * 16 + laneN;
                const float bb = bias[gn];
                #pragma unroll
                for (int r = 0; r < 4; ++r)
                    Cf[(size_t)(gm0 + r) * N + gn] = acc[ms][ns][r] + bb;
            }
        }
    } else {
        #pragma unroll
        for (int ms = 0; ms < 4; ++ms) {
            const int gm0 = rm0 + wr + ms * 16 + quad * 4;
            #pragma unroll
            for (int ns = 0; ns < 4; ++ns) {
                const int gn = rn0 + wc + ns * 16 + laneN;
                const float bb = bias[gn];
                const int s = gn >> 10, rr = gn & 1023, hh = rr >> 6, dd = rr & 63;
                #pragma unroll
                for (int r = 0; r < 4; ++r) {
                    const int gm = gm0 + r;
                    const int bidx = gm >> 11, t = gm & (T_ - 1);
                    const unsigned short val = f2bf(acc[ms][ns][r] + bb);
                    const int bh = bidx * H_ + hh;
                    if (s == 0)      Qo[((size_t)bh * T_ + t) * HD_ + dd] = val;
                    else if (s == 1) Ko[((size_t)bh * T_ + t) * HD_ + dd] = val;
                    else             Vo[((size_t)bh * HD_ + dd) * T_ + t] = val;
                }
            }
        }
    }
}

// ---------------- flash attention, S^T register trick ----------------
// grid(T/128, B*H), 256 thr (4 waves). Wave: 32 Q-rows (2 qgroups of 16).
// Q,K: [B*H, T, 64] bf16 ; VT: [B*H, 64, T] bf16 ; Out: [B*T, 1024] bf16.
// S^T = MFMA32(A=K, B=Q): lane holds q=laneN, key=quad*4+r (+mt*16) —
// exactly the A-operand layout of MFMA16 -> PV consumes P from registers.
// Main loop is barrier-free (no LDS transpose).
__global__ __launch_bounds__(256, 4)
void attn_kernel(const unsigned short* __restrict__ Q,
                 const unsigned short* __restrict__ Kb,
                 const unsigned short* __restrict__ VT,
                 const int* __restrict__ mask,
                 unsigned short* __restrict__ Out) {
    __shared__ float biasLds[T_];
    const int tid = threadIdx.x;
    const int lane = tid & 63;
    const int w = tid >> 6;
    const int laneN = lane & 15, quad = lane >> 4;
    const int bh = blockIdx.y;
    const int b = bh >> 4, h = bh & 15;
    const int qbase = blockIdx.x * 128 + w * 32;

    // mask -> additive bias in base-2 softmax domain, hoisted once per block
    for (int i = tid; i < T_; i += 256)
        biasLds[i] = mask[b * T_ + i] ? 0.f : -1.44269504e9f;
    __syncthreads();

    const float scl = 0.125f * 1.44269504088896f;   // 1/sqrt(64) * log2(e)

    // Q B-operand frags: [qg][k-half], kept in registers for all tiles
    s16x8 qf[2][2];
    #pragma unroll
    for (int qg = 0; qg < 2; ++qg) {
        const size_t qoff = ((size_t)bh * T_ + qbase + qg * 16 + laneN) * HD_ + quad * 8;
        qf[qg][0] = *(const s16x8*)&Q[qoff];
        qf[qg][1] = *(const s16x8*)&Q[qoff + 32];
    }

    float mi[2] = {-3.0e38f, -3.0e38f};
    float li[2] = {0.f, 0.f};
    f32x4 O[2][4] = {};        // [qg][ntile]; lane holds q=quad*4+r, d=nt*16+laneN

    for (int kt = 0; kt < T_ / 64; ++kt) {
        const int kbase = kt * 64;

        // ---- S^T = K @ Q^T ----
        f32x4 S[2][4];         // [qg][mtile]; lane holds q=laneN, key=mt*16+quad*4+r
        #pragma unroll
        for (int mt = 0; mt < 4; ++mt) {
            const size_t koff = ((size_t)bh * T_ + kbase + mt * 16 + laneN) * HD_ + quad * 8;
            const s16x8 k0 = *(const s16x8*)&Kb[koff];
            const s16x8 k1 = *(const s16x8*)&Kb[koff + 32];
            #pragma unroll
            for (int qg = 0; qg < 2; ++qg) {
                f32x4 s = {};
                s = MFMA32(k0, qf[qg][0], s);
                s = MFMA32(k1, qf[qg][1], s);
                S[qg][mt] = s;
            }
        }

        // ---- scale + mask bias ----
        f32x4 bias4[4];
        #pragma unroll
        for (int mt = 0; mt < 4; ++mt)
            bias4[mt] = *(const f32x4*)&biasLds[kbase + mt * 16 + quad * 4];
        #pragma unroll
        for (int qg = 0; qg < 2; ++qg)
            #pragma unroll
            for (int mt = 0; mt < 4; ++mt)
                #pragma unroll
                for (int r = 0; r < 4; ++r)
                    S[qg][mt][r] = S[qg][mt][r] * scl + bias4[mt][r];

        // ---- online softmax (base-2); row stats live at lane laneN=q ----
        s16x4 pf[2][4];
        float al[2][4];
        #pragma unroll
        for (int qg = 0; qg < 2; ++qg) {
            float rmax = -3.0e38f;
            #pragma unroll
            for (int mt = 0; mt < 4; ++mt)
                #pragma unroll
                for (int r = 0; r < 4; ++r)
                    rmax = fmaxf(rmax, S[qg][mt][r]);
            rmax = fmaxf(rmax, __shfl_xor(rmax, 16));
            rmax = fmaxf(rmax, __shfl_xor(rmax, 32));
            const float mnew = fmaxf(mi[qg], rmax);
            const float alpha = exp2f(mi[qg] - mnew);
            mi[qg] = mnew;
            float rsum = 0.f;
            #pragma unroll
            for (int mt = 0; mt < 4; ++mt) {
                #pragma unroll
                for (int r = 0; r < 4; ++r) {
                    const float p = exp2f(S[qg][mt][r] - mnew);
                    S[qg][mt][r] = p;
                    rsum += p;
                }
                union { s16x4 v; unsigned int u[2]; } pu;
                pu.u[0] = pkbf(S[qg][mt][0], S[qg][mt][1]);
                pu.u[1] = pkbf(S[qg][mt][2], S[qg][mt][3]);
                pf[qg][mt] = pu.v;
            }
            rsum += __shfl_xor(rsum, 16);
            rsum += __shfl_xor(rsum, 32);
            li[qg] = li[qg] * alpha + rsum;
            // broadcast alpha from S-domain (q=laneN) to O-domain (q=quad*4+r)
            #pragma unroll
            for (int r = 0; r < 4; ++r)
                al[qg][r] = __shfl(alpha, quad * 4 + r);
        }

        // ---- O = O*alpha + P @ V (P straight from registers) ----
        #pragma unroll
        for (int qg = 0; qg < 2; ++qg)
            #pragma unroll
            for (int nt = 0; nt < 4; ++nt)
                #pragma unroll
                for (int r = 0; r < 4; ++r)
                    O[qg][nt][r] *= al[qg][r];
        #pragma unroll
        for (int mt = 0; mt < 4; ++mt) {
            s16x4 vf[4];
            #pragma unroll
            for (int nt = 0; nt < 4; ++nt)
                vf[nt] = *(const s16x4*)&VT[((size_t)bh * HD_ + nt * 16 + laneN) * T_
                                            + kbase + mt * 16 + quad * 4];
            #pragma unroll
            for (int qg = 0; qg < 2; ++qg)
                #pragma unroll
                for (int nt = 0; nt < 4; ++nt)
                    O[qg][nt] = MFMA16(pf[qg][mt], vf[nt], O[qg][nt]);
        }
    }

    // ---- epilogue: Out[b,t, h*64+d] bf16 ----
    #pragma unroll
    for (int qg = 0; qg < 2; ++qg) {
        const float inv = 1.0f / li[qg];
        float invr[4];
        #pragma unroll
        for (int r = 0; r < 4; ++r)
            invr[r] = __shfl(inv, quad * 4 + r);
        #pragma unroll
        for (int nt = 0; nt < 4; ++nt)
            #pragma unroll
            for (int r = 0; r < 4; ++r) {
                const int tq = qbase + qg * 16 + quad * 4 + r;
                Out[(size_t)(b * T_ + tq) * D_ + h * HD_ + nt * 16 + laneN] =
                    f2bf(O[qg][nt][r] * invr[r]);
            }
    }
}

extern "C" void kernel_launch(void* const* d_in, const int* in_sizes, int n_in,
                              void* d_out, int out_size, void* d_ws, size_t ws_size,
                              hipStream_t stream) {
    const float* x     = (const float*)d_in[0];
    const int*   mask  = (const int*)d_in[1];
    const float* W_qkv = (const float*)d_in[2];
    const float* b_qkv = (const float*)d_in[3];
    const float* W_out = (const float*)d_in[4];
    const float* b_out = (const float*)d_in[5];
    float* out = (float*)d_out;

    unsigned short* ws = (unsigned short*)d_ws;
    const size_t NX = (size_t)B_ * T_ * D_;          // 8388608
    unsigned short* xb  = ws;                        // x bf16; reused for attn out
    unsigned short* Qb  = xb + NX;
    unsigned short* Kb  = Qb + NX;
    unsigned short* Vtb = Kb + NX;
    unsigned short* Wqt = Vtb + NX;                  // [3D, D]
    unsigned short* Wot = Wqt + (size_t)3 * D_ * D_; // [D, D]
    unsigned short* attn = xb;                       // alias: xb dead after GEMM1

    cast_bf16_kernel<<<(int)(NX / 4 + 255) / 256, 256, 0, stream>>>(x, xb, (int)(NX / 4));
    {
        dim3 blk(32, 8), grd(3 * D_ / 32, D_ / 32);
        transpose_cast_kernel<<<grd, blk, 0, stream>>>(W_qkv, Wqt, D_, 3 * D_);
    }
    {
        dim3 blk(32, 8), grd(D_ / 32, D_ / 32);
        transpose_cast_kernel<<<grd, blk, 0, stream>>>(W_out, Wot, D_, D_);
    }
    gemm_bt_kernel<1><<<dim3(3 * D_ / 128, B_ * T_ / 128), 256, 0, stream>>>(
        xb, Wqt, b_qkv, nullptr, Qb, Kb, Vtb, B_ * T_, 3 * D_, D_);
    attn_kernel<<<dim3(T_ / 128, B_ * H_), 256, 0, stream>>>(Qb, Kb, Vtb, mask, attn);
    gemm_bt_kernel<0><<<dim3(D_ / 128, B_ * T_ / 128), 256, 0, stream>>>(
        attn, Wot, b_out, out, nullptr, nullptr, nullptr, B_ * T_, D_, D_);
}

// Round 3
// 404.829 us; speedup vs baseline: 1.9836x; 1.4425x over previous
//
#include <hip/hip_runtime.h>
#include <hip/hip_bf16.h>
#include <stdint.h>

// ---- problem constants ----
#define B_  4
#define T_  2048
#define D_  1024
#define H_  16
#define HD_ 64

typedef short s16x8 __attribute__((ext_vector_type(8)));
typedef short s16x4 __attribute__((ext_vector_type(4)));
typedef float f32x4 __attribute__((ext_vector_type(4)));

#define MFMA32(a, b, c) __builtin_amdgcn_mfma_f32_16x16x32_bf16(a, b, c, 0, 0, 0)
#define MFMA16(a, b, c) __builtin_amdgcn_mfma_f32_16x16x16bf16_1k(a, b, c, 0, 0, 0)

__device__ __forceinline__ unsigned short f2bf(float f) {
    union { float f; unsigned int u; } v; v.f = f;
    unsigned int r = v.u + 0x7fffu + ((v.u >> 16) & 1u);   // RNE
    return (unsigned short)(r >> 16);
}

__device__ __forceinline__ unsigned int pkbf(float a, float b) {
    __hip_bfloat162 h = __float22bfloat162_rn(float2{a, b});  // v_cvt_pk_bf16_f32
    union { __hip_bfloat162 h; unsigned int u; } v; v.h = h;
    return v.u;
}

__device__ __forceinline__ void async16(const void* g, void* l) {
    __builtin_amdgcn_global_load_lds(
        (const __attribute__((address_space(1))) unsigned int*)g,
        (__attribute__((address_space(3))) unsigned int*)l, 16, 0, 0);
}

// ---------------- cast x (fp32 -> bf16), 4 elems/thread ----------------
__global__ void cast_bf16_kernel(const float* __restrict__ in,
                                 unsigned short* __restrict__ out, int n4) {
    int i = blockIdx.x * 256 + threadIdx.x;
    if (i < n4) {
        float4 v = ((const float4*)in)[i];
        ushort4 o;
        o.x = f2bf(v.x); o.y = f2bf(v.y); o.z = f2bf(v.z); o.w = f2bf(v.w);
        ((ushort4*)out)[i] = o;
    }
}

// ------------- transpose+cast: W[K,N] fp32 -> Wt[N,K] bf16 -------------
__global__ void transpose_cast_kernel(const float* __restrict__ W,
                                      unsigned short* __restrict__ Wt,
                                      int K, int N) {
    __shared__ float t[32][33];
    const int bx = blockIdx.x * 32;   // n
    const int by = blockIdx.y * 32;   // k
    const int tx = threadIdx.x, ty = threadIdx.y;
    #pragma unroll
    for (int j = 0; j < 32; j += 8)
        t[ty + j][tx] = W[(size_t)(by + ty + j) * N + bx + tx];
    __syncthreads();
    #pragma unroll
    for (int j = 0; j < 32; j += 8)
        Wt[(size_t)(bx + ty + j) * K + by + tx] = f2bf(t[tx][ty + j]);
}

// ---------------- bf16 MFMA GEMM: C = A[M,K] @ Bt[N,K]^T + bias --------
// MODE 0: Cf = acc + bias (fp32). MODE 1: QKV scatter; Q pre-scaled by
// 0.125*log2e so attention softmax runs in base-2 with no per-S multiply.
template <int MODE>
__global__ __launch_bounds__(256)
void gemm_bt_kernel(const unsigned short* __restrict__ A,
                    const unsigned short* __restrict__ Bt,
                    const float* __restrict__ bias,
                    float* __restrict__ Cf,
                    unsigned short* __restrict__ Qo,
                    unsigned short* __restrict__ Ko,
                    unsigned short* __restrict__ Vo,
                    int M, int N, int K) {
    __shared__ __align__(16) unsigned short As[128 * 32];
    __shared__ __align__(16) unsigned short Bs[128 * 32];
    const int tid = threadIdx.x;
    const int w = tid >> 6, lane = tid & 63;
    const int laneN = lane & 15, quad = lane >> 4;
    const int rm0 = blockIdx.y * 128, rn0 = blockIdx.x * 128;
    const int wr = (w >> 1) * 64, wc = (w & 1) * 64;

    f32x4 acc[4][4] = {};

    for (int kk = 0; kk < K; kk += 32) {
        #pragma unroll
        for (int i = 0; i < 2; ++i) {
            const int c = (w * 2 + i) * 64 + lane;   // 0..511 chunk id
            const int row = c >> 2, k2 = c & 3;
            async16(A  + (size_t)(rm0 + row) * K + kk + k2 * 8, (char*)As + (size_t)c * 16);
            async16(Bt + (size_t)(rn0 + row) * K + kk + k2 * 8, (char*)Bs + (size_t)c * 16);
        }
        __syncthreads();
        s16x8 av[4], bv[4];
        #pragma unroll
        for (int ms = 0; ms < 4; ++ms)
            av[ms] = *(const s16x8*)&As[(wr + ms * 16 + laneN) * 32 + quad * 8];
        #pragma unroll
        for (int ns = 0; ns < 4; ++ns)
            bv[ns] = *(const s16x8*)&Bs[(wc + ns * 16 + laneN) * 32 + quad * 8];
        #pragma unroll
        for (int ms = 0; ms < 4; ++ms)
            #pragma unroll
            for (int ns = 0; ns < 4; ++ns)
                acc[ms][ns] = MFMA32(av[ms], bv[ns], acc[ms][ns]);
        __syncthreads();
    }

    if (MODE == 0) {
        #pragma unroll
        for (int ms = 0; ms < 4; ++ms) {
            const int gm0 = rm0 + wr + ms * 16 + quad * 4;
            #pragma unroll
            for (int ns = 0; ns < 4; ++ns) {
                const int gn = rn0 + wc + ns * 16 + laneN;
                const float bb = bias[gn];
                #pragma unroll
                for (int r = 0; r < 4; ++r)
                    Cf[(size_t)(gm0 + r) * N + gn] = acc[ms][ns][r] + bb;
            }
        }
    } else {
        const float qscl = 0.125f * 1.44269504088896f;   // 1/sqrt(64)*log2(e)
        #pragma unroll
        for (int ms = 0; ms < 4; ++ms) {
            const int gm0 = rm0 + wr + ms * 16 + quad * 4;
            #pragma unroll
            for (int ns = 0; ns < 4; ++ns) {
                const int gn = rn0 + wc + ns * 16 + laneN;
                const float bb = bias[gn];
                const int s = gn >> 10, rr = gn & 1023, hh = rr >> 6, dd = rr & 63;
                #pragma unroll
                for (int r = 0; r < 4; ++r) {
                    const int gm = gm0 + r;
                    const int bidx = gm >> 11, t = gm & (T_ - 1);
                    float vacc = acc[ms][ns][r] + bb;
                    if (s == 0) vacc *= qscl;
                    const unsigned short val = f2bf(vacc);
                    const int bh = bidx * H_ + hh;
                    if (s == 0)      Qo[((size_t)bh * T_ + t) * HD_ + dd] = val;
                    else if (s == 1) Ko[((size_t)bh * T_ + t) * HD_ + dd] = val;
                    else             Vo[((size_t)bh * HD_ + dd) * T_ + t] = val;
                }
            }
        }
    }
}

// ---------------- flash attention, S^T trick + LDS-staged K/V ----------
// grid(T/128, B*H), 256 thr (4 waves). Wave: 32 Q-rows (2 qgroups of 16).
// K,V tiles (64 keys) double-buffered in LDS via global_load_lds(16),
// shared across the 4 waves; one barrier/tile; prefetch kt+1 overlaps
// compute of kt. Global-side XOR swizzle (slot s = chunk g ^ (row&7))
// keeps staging 128B-coalesced AND frag ds_reads at the bank floor.
__global__ __launch_bounds__(256, 4)
void attn_kernel(const unsigned short* __restrict__ Q,
                 const unsigned short* __restrict__ Kb,
                 const unsigned short* __restrict__ VT,
                 const int* __restrict__ mask,
                 unsigned short* __restrict__ Out) {
    __shared__ __align__(16) unsigned short Ks[2][64 * 64];  // [key][d] swizzled
    __shared__ __align__(16) unsigned short Vs[2][64 * 64];  // [d][key] swizzled
    __shared__ unsigned short biasB[T_];                     // bf16 mask bias
    const int tid = threadIdx.x;
    const int lane = tid & 63;
    const int w = tid >> 6;
    const int laneN = lane & 15, quad = lane >> 4;
    const int x7 = laneN & 7;
    const int bh = blockIdx.y;
    const int b = bh >> 4, h = bh & 15;
    const int qbase = blockIdx.x * 128 + w * 32;

    const unsigned short negbig = f2bf(-1.0e9f);
    for (int i = tid; i < T_; i += 256)
        biasB[i] = mask[b * T_ + i] ? (unsigned short)0 : negbig;

    // Q B-operand frags (already scaled by 0.125*log2e in GEMM1 epilogue)
    s16x8 qf[2][2];
    #pragma unroll
    for (int qg = 0; qg < 2; ++qg) {
        const size_t qoff = ((size_t)bh * T_ + qbase + qg * 16 + laneN) * HD_ + quad * 8;
        qf[qg][0] = *(const s16x8*)&Q[qoff];
        qf[qg][1] = *(const s16x8*)&Q[qoff + 32];
    }

    const size_t kRow0 = (size_t)bh * T_ * HD_;
    const size_t vRow0 = (size_t)bh * HD_ * T_;

    auto issueTile = [&](int kt, int bufsel) {
        const int kbase = kt * 64;
        #pragma unroll
        for (int i = 0; i < 2; ++i) {
            const int c = i * 256 + tid;                       // 512 K chunks
            const int row = c >> 3, s = c & 7, g = s ^ (row & 7);
            async16(Kb + kRow0 + (size_t)(kbase + row) * HD_ + g * 8,
                    &Ks[bufsel][c * 8]);
        }
        #pragma unroll
        for (int i = 0; i < 2; ++i) {
            const int c = i * 256 + tid;                       // 512 V chunks
            const int d = c >> 3, s = c & 7, g = s ^ (d & 7);
            async16(VT + vRow0 + (size_t)d * T_ + kbase + g * 8,
                    &Vs[bufsel][c * 8]);
        }
    };

    issueTile(0, 0);

    float mi[2] = {-3.0e38f, -3.0e38f};
    float li[2] = {0.f, 0.f};
    f32x4 O[2][4] = {};        // [qg][ntile]; lane: q=quad*4+r, d=nt*16+laneN

    for (int kt = 0; kt < T_ / 64; ++kt) {
        const int buf = kt & 1;
        const int kbase = kt * 64;
        __syncthreads();                       // buf ready; buf^1 free
        if (kt + 1 < T_ / 64) issueTile(kt + 1, buf ^ 1);

        // ---- S^T = K @ Q^T from LDS ----
        f32x4 S[2][4];         // [qg][mt]; lane: q=laneN, key=mt*16+quad*4+r
        #pragma unroll
        for (int mt = 0; mt < 4; ++mt) {
            const int srow = (mt * 16 + laneN) * 8;
            const s16x8 k0 = *(const s16x8*)&Ks[buf][(srow + (quad ^ x7)) * 8];
            const s16x8 k1 = *(const s16x8*)&Ks[buf][(srow + ((4 + quad) ^ x7)) * 8];
            #pragma unroll
            for (int qg = 0; qg < 2; ++qg) {
                f32x4 s = {};
                s = MFMA32(k0, qf[qg][0], s);
                s = MFMA32(k1, qf[qg][1], s);
                S[qg][mt] = s;
            }
        }

        // ---- mask bias add (bf16 table -> f32 via <<16) ----
        #pragma unroll
        for (int mt = 0; mt < 4; ++mt) {
            const s16x4 bu = *(const s16x4*)&biasB[kbase + mt * 16 + quad * 4];
            #pragma unroll
            for (int r = 0; r < 4; ++r) {
                union { unsigned u; float f; } cv;
                cv.u = ((unsigned)(unsigned short)bu[r]) << 16;
                #pragma unroll
                for (int qg = 0; qg < 2; ++qg)
                    S[qg][mt][r] += cv.f;
            }
        }

        // ---- online softmax (base-2); row stats at lane laneN=q ----
        s16x4 pf[2][4];
        float al[2][4];
        #pragma unroll
        for (int qg = 0; qg < 2; ++qg) {
            float rmax = -3.0e38f;
            #pragma unroll
            for (int mt = 0; mt < 4; ++mt)
                #pragma unroll
                for (int r = 0; r < 4; ++r)
                    rmax = fmaxf(rmax, S[qg][mt][r]);
            rmax = fmaxf(rmax, __shfl_xor(rmax, 16));
            rmax = fmaxf(rmax, __shfl_xor(rmax, 32));
            const float mnew = fmaxf(mi[qg], rmax);
            const float alpha = exp2f(mi[qg] - mnew);
            mi[qg] = mnew;
            float rsum = 0.f;
            #pragma unroll
            for (int mt = 0; mt < 4; ++mt) {
                #pragma unroll
                for (int r = 0; r < 4; ++r) {
                    const float p = exp2f(S[qg][mt][r] - mnew);
                    S[qg][mt][r] = p;
                    rsum += p;
                }
                union { s16x4 v; unsigned int u[2]; } pu;
                pu.u[0] = pkbf(S[qg][mt][0], S[qg][mt][1]);
                pu.u[1] = pkbf(S[qg][mt][2], S[qg][mt][3]);
                pf[qg][mt] = pu.v;
            }
            rsum += __shfl_xor(rsum, 16);
            rsum += __shfl_xor(rsum, 32);
            li[qg] = li[qg] * alpha + rsum;
            #pragma unroll
            for (int r = 0; r < 4; ++r)
                al[qg][r] = __shfl(alpha, quad * 4 + r);
        }

        // ---- O = O*alpha + P @ V (P from registers, V from LDS) ----
        #pragma unroll
        for (int qg = 0; qg < 2; ++qg)
            #pragma unroll
            for (int nt = 0; nt < 4; ++nt)
                #pragma unroll
                for (int r = 0; r < 4; ++r)
                    O[qg][nt][r] *= al[qg][r];
        #pragma unroll
        for (int mt = 0; mt < 4; ++mt) {
            const int sv = mt * 2 + (quad >> 1);
            s16x4 vf[4];
            #pragma unroll
            for (int nt = 0; nt < 4; ++nt) {
                const int d = nt * 16 + laneN;
                vf[nt] = *(const s16x4*)&Vs[buf][(d * 8 + (sv ^ x7)) * 8 + (quad & 1) * 4];
            }
            #pragma unroll
            for (int qg = 0; qg < 2; ++qg)
                #pragma unroll
                for (int nt = 0; nt < 4; ++nt)
                    O[qg][nt] = MFMA16(pf[qg][mt], vf[nt], O[qg][nt]);
        }
    }

    // ---- epilogue: Out[b,t, h*64+d] bf16 ----
    #pragma unroll
    for (int qg = 0; qg < 2; ++qg) {
        const float inv = 1.0f / li[qg];
        float invr[4];
        #pragma unroll
        for (int r = 0; r < 4; ++r)
            invr[r] = __shfl(inv, quad * 4 + r);
        #pragma unroll
        for (int nt = 0; nt < 4; ++nt)
            #pragma unroll
            for (int r = 0; r < 4; ++r) {
                const int tq = qbase + qg * 16 + quad * 4 + r;
                Out[(size_t)(b * T_ + tq) * D_ + h * HD_ + nt * 16 + laneN] =
                    f2bf(O[qg][nt][r] * invr[r]);
            }
    }
}

extern "C" void kernel_launch(void* const* d_in, const int* in_sizes, int n_in,
                              void* d_out, int out_size, void* d_ws, size_t ws_size,
                              hipStream_t stream) {
    const float* x     = (const float*)d_in[0];
    const int*   mask  = (const int*)d_in[1];
    const float* W_qkv = (const float*)d_in[2];
    const float* b_qkv = (const float*)d_in[3];
    const float* W_out = (const float*)d_in[4];
    const float* b_out = (const float*)d_in[5];
    float* out = (float*)d_out;

    unsigned short* ws = (unsigned short*)d_ws;
    const size_t NX = (size_t)B_ * T_ * D_;          // 8388608
    unsigned short* xb  = ws;                        // x bf16; reused for attn out
    unsigned short* Qb  = xb + NX;
    unsigned short* Kb  = Qb + NX;
    unsigned short* Vtb = Kb + NX;
    unsigned short* Wqt = Vtb + NX;                  // [3D, D]
    unsigned short* Wot = Wqt + (size_t)3 * D_ * D_; // [D, D]
    unsigned short* attn = xb;                       // alias: xb dead after GEMM1

    cast_bf16_kernel<<<(int)(NX / 4 + 255) / 256, 256, 0, stream>>>(x, xb, (int)(NX / 4));
    {
        dim3 blk(32, 8), grd(3 * D_ / 32, D_ / 32);
        transpose_cast_kernel<<<grd, blk, 0, stream>>>(W_qkv, Wqt, D_, 3 * D_);
    }
    {
        dim3 blk(32, 8), grd(D_ / 32, D_ / 32);
        transpose_cast_kernel<<<grd, blk, 0, stream>>>(W_out, Wot, D_, D_);
    }
    gemm_bt_kernel<1><<<dim3(3 * D_ / 128, B_ * T_ / 128), 256, 0, stream>>>(
        xb, Wqt, b_qkv, nullptr, Qb, Kb, Vtb, B_ * T_, 3 * D_, D_);
    attn_kernel<<<dim3(T_ / 128, B_ * H_), 256, 0, stream>>>(Qb, Kb, Vtb, mask, attn);
    gemm_bt_kernel<0><<<dim3(D_ / 128, B_ * T_ / 128), 256, 0, stream>>>(
        attn, Wot, b_out, out, nullptr, nullptr, nullptr, B_ * T_, D_, D_);
}

// Round 4
// 355.953 us; speedup vs baseline: 2.2560x; 1.1373x over previous
//
#include <hip/hip_runtime.h>
#include <hip/hip_bf16.h>
#include <stdint.h>

// ---- problem constants ----
#define B_  4
#define T_  2048
#define D_  1024
#define H_  16
#define HD_ 64

typedef short s16x8 __attribute__((ext_vector_type(8)));
typedef short s16x4 __attribute__((ext_vector_type(4)));
typedef float f32x4 __attribute__((ext_vector_type(4)));

#define MFMA32(a, b, c) __builtin_amdgcn_mfma_f32_16x16x32_bf16(a, b, c, 0, 0, 0)

__device__ __forceinline__ unsigned short f2bf(float f) {
    union { float f; unsigned int u; } v; v.f = f;
    unsigned int r = v.u + 0x7fffu + ((v.u >> 16) & 1u);   // RNE
    return (unsigned short)(r >> 16);
}

__device__ __forceinline__ unsigned int pkbf(float a, float b) {
    __hip_bfloat162 h = __float22bfloat162_rn(float2{a, b});  // v_cvt_pk_bf16_f32
    union { __hip_bfloat162 h; unsigned int u; } v; v.h = h;
    return v.u;
}

__device__ __forceinline__ void async16(const void* g, void* l) {
    __builtin_amdgcn_global_load_lds(
        (const __attribute__((address_space(1))) unsigned int*)g,
        (__attribute__((address_space(3))) unsigned int*)l, 16, 0, 0);
}

// ---------------- cast x (fp32 -> bf16), 4 elems/thread ----------------
__global__ void cast_bf16_kernel(const float* __restrict__ in,
                                 unsigned short* __restrict__ out, int n4) {
    int i = blockIdx.x * 256 + threadIdx.x;
    if (i < n4) {
        float4 v = ((const float4*)in)[i];
        ushort4 o;
        o.x = f2bf(v.x); o.y = f2bf(v.y); o.z = f2bf(v.z); o.w = f2bf(v.w);
        ((ushort4*)out)[i] = o;
    }
}

// ------------- transpose+cast: W[K,N] fp32 -> Wt[N,K] bf16 -------------
__global__ void transpose_cast_kernel(const float* __restrict__ W,
                                      unsigned short* __restrict__ Wt,
                                      int K, int N) {
    __shared__ float t[32][33];
    const int bx = blockIdx.x * 32;   // n
    const int by = blockIdx.y * 32;   // k
    const int tx = threadIdx.x, ty = threadIdx.y;
    #pragma unroll
    for (int j = 0; j < 32; j += 8)
        t[ty + j][tx] = W[(size_t)(by + ty + j) * N + bx + tx];
    __syncthreads();
    #pragma unroll
    for (int j = 0; j < 32; j += 8)
        Wt[(size_t)(bx + ty + j) * K + by + tx] = f2bf(t[tx][ty + j]);
}

// ---------------- bf16 MFMA GEMM: C = A[M,K] @ Bt[N,K]^T + bias --------
// MODE 0: Cf = acc + bias (fp32). MODE 1: QKV scatter; Q pre-scaled by
// 0.125*log2e so attention softmax runs in base-2 with no per-S multiply.
template <int MODE>
__global__ __launch_bounds__(256)
void gemm_bt_kernel(const unsigned short* __restrict__ A,
                    const unsigned short* __restrict__ Bt,
                    const float* __restrict__ bias,
                    float* __restrict__ Cf,
                    unsigned short* __restrict__ Qo,
                    unsigned short* __restrict__ Ko,
                    unsigned short* __restrict__ Vo,
                    int M, int N, int K) {
    __shared__ __align__(16) unsigned short As[128 * 32];
    __shared__ __align__(16) unsigned short Bs[128 * 32];
    const int tid = threadIdx.x;
    const int w = tid >> 6, lane = tid & 63;
    const int laneN = lane & 15, quad = lane >> 4;
    const int rm0 = blockIdx.y * 128, rn0 = blockIdx.x * 128;
    const int wr = (w >> 1) * 64, wc = (w & 1) * 64;

    f32x4 acc[4][4] = {};

    for (int kk = 0; kk < K; kk += 32) {
        #pragma unroll
        for (int i = 0; i < 2; ++i) {
            const int c = (w * 2 + i) * 64 + lane;   // 0..511 chunk id
            const int row = c >> 2, k2 = c & 3;
            async16(A  + (size_t)(rm0 + row) * K + kk + k2 * 8, (char*)As + (size_t)c * 16);
            async16(Bt + (size_t)(rn0 + row) * K + kk + k2 * 8, (char*)Bs + (size_t)c * 16);
        }
        __syncthreads();
        s16x8 av[4], bv[4];
        #pragma unroll
        for (int ms = 0; ms < 4; ++ms)
            av[ms] = *(const s16x8*)&As[(wr + ms * 16 + laneN) * 32 + quad * 8];
        #pragma unroll
        for (int ns = 0; ns < 4; ++ns)
            bv[ns] = *(const s16x8*)&Bs[(wc + ns * 16 + laneN) * 32 + quad * 8];
        #pragma unroll
        for (int ms = 0; ms < 4; ++ms)
            #pragma unroll
            for (int ns = 0; ns < 4; ++ns)
                acc[ms][ns] = MFMA32(av[ms], bv[ns], acc[ms][ns]);
        __syncthreads();
    }

    if (MODE == 0) {
        #pragma unroll
        for (int ms = 0; ms < 4; ++ms) {
            const int gm0 = rm0 + wr + ms * 16 + quad * 4;
            #pragma unroll
            for (int ns = 0; ns < 4; ++ns) {
                const int gn = rn0 + wc + ns * 16 + laneN;
                const float bb = bias[gn];
                #pragma unroll
                for (int r = 0; r < 4; ++r)
                    Cf[(size_t)(gm0 + r) * N + gn] = acc[ms][ns][r] + bb;
            }
        }
    } else {
        const float qscl = 0.125f * 1.44269504088896f;   // 1/sqrt(64)*log2(e)
        #pragma unroll
        for (int ms = 0; ms < 4; ++ms) {
            const int gm0 = rm0 + wr + ms * 16 + quad * 4;
            #pragma unroll
            for (int ns = 0; ns < 4; ++ns) {
                const int gn = rn0 + wc + ns * 16 + laneN;
                const float bb = bias[gn];
                const int s = gn >> 10, rr = gn & 1023, hh = rr >> 6, dd = rr & 63;
                #pragma unroll
                for (int r = 0; r < 4; ++r) {
                    const int gm = gm0 + r;
                    const int bidx = gm >> 11, t = gm & (T_ - 1);
                    float vacc = acc[ms][ns][r] + bb;
                    if (s == 0) vacc *= qscl;
                    const unsigned short val = f2bf(vacc);
                    const int bh = bidx * H_ + hh;
                    if (s == 0)      Qo[((size_t)bh * T_ + t) * HD_ + dd] = val;
                    else if (s == 1) Ko[((size_t)bh * T_ + t) * HD_ + dd] = val;
                    else             Vo[((size_t)bh * HD_ + dd) * T_ + t] = val;
                }
            }
        }
    }
}

// ---------------- flash attention v4 ----------------
// grid(B*H, T/128): all q-blocks of one head land on one XCD (round-robin
// % 8 over 64-wide x) -> K/V stay L2-resident.  256 thr (4 waves), 32
// q-rows/wave.  Fixed-max base-2 softmax (scores are O(1) by construction;
// exp2 overflow margin ~2^120) -> no per-tile shuffles / rescale.
// S^T computed with PERMUTED K-rows so its C-layout concatenates into the
// 16x16x32 A-operand (k=quad*8+j) -> PV and row-sum (B=ones) run as MFMA32
// straight from registers.  K/V double-buffered in LDS via global_load_lds,
// XOR-swizzled; one barrier/tile.
__global__ __launch_bounds__(256, 4)
void attn_kernel(const unsigned short* __restrict__ Q,
                 const unsigned short* __restrict__ Kb,
                 const unsigned short* __restrict__ VT,
                 const int* __restrict__ mask,
                 unsigned short* __restrict__ Out) {
    __shared__ __align__(16) unsigned short Ks[2][64 * 64];  // [key][d] swizzled
    __shared__ __align__(16) unsigned short Vs[2][64 * 64];  // [d][key] swizzled
    __shared__ float biasF[T_];                              // fp32 mask bias
    const int tid = threadIdx.x;
    const int lane = tid & 63;
    const int w = tid >> 6;
    const int laneN = lane & 15, quad = lane >> 4;
    const int x7 = laneN & 7;
    const int bh = blockIdx.x;
    const int b = bh >> 4, h = bh & 15;
    const int qbase = blockIdx.y * 128 + w * 32;

    for (int i = tid; i < T_; i += 256)
        biasF[i] = mask[b * T_ + i] ? 0.f : -1.0e9f;

    // Q B-operand frags (pre-scaled by 0.125*log2e in GEMM1 epilogue)
    s16x8 qf[2][2];
    #pragma unroll
    for (int qg = 0; qg < 2; ++qg) {
        const size_t qoff = ((size_t)bh * T_ + qbase + qg * 16 + laneN) * HD_ + quad * 8;
        qf[qg][0] = *(const s16x8*)&Q[qoff];
        qf[qg][1] = *(const s16x8*)&Q[qoff + 32];
    }

    s16x8 ones;
    #pragma unroll
    for (int j = 0; j < 8; ++j) ones[j] = (short)0x3F80;   // bf16 1.0

    const size_t kRow0 = (size_t)bh * T_ * HD_;
    const size_t vRow0 = (size_t)bh * HD_ * T_;

    // K swizzle f(row) = (row&3) | (((row>>3)&1)<<2); V swizzle f(d) = d&7
    auto issueTile = [&](int kt, int bufsel) {
        const int kbase = kt * 64;
        #pragma unroll
        for (int i = 0; i < 2; ++i) {
            const int c = i * 256 + tid;                    // 512 K chunks
            const int row = c >> 3, s = c & 7;
            const int fk = (row & 3) | (((row >> 3) & 1) << 2);
            const int g = s ^ fk;
            async16(Kb + kRow0 + (size_t)(kbase + row) * HD_ + g * 8,
                    &Ks[bufsel][c * 8]);
        }
        #pragma unroll
        for (int i = 0; i < 2; ++i) {
            const int c = i * 256 + tid;                    // 512 V chunks
            const int d = c >> 3, s = c & 7, g = s ^ (d & 7);
            async16(VT + vRow0 + (size_t)d * T_ + kbase + g * 8,
                    &Vs[bufsel][c * 8]);
        }
    };

    issueTile(0, 0);

    f32x4 O[2][4] = {};        // [qg][nt]; lane: q=quad*4+r, d=nt*16+laneN
    f32x4 liacc[2] = {};       // [qg]; lane: q=quad*4+r (row-sums via MFMA)

    // permuted K rows: rowA(laneN) covers keys quad*8+r after MFMA
    const int rowA = ((laneN >> 2) << 3) + (laneN & 3);     // +4 -> twin half

    for (int kt = 0; kt < T_ / 64; ++kt) {
        const int buf = kt & 1;
        const int kbase = kt * 64;
        __syncthreads();                       // buf ready; buf^1 free
        if (kt + 1 < T_ / 64) issueTile(kt + 1, buf ^ 1);

        s16x8 pf[2][2];        // [qg][g32] A-operand P frags (k=quad*8+j)
        #pragma unroll
        for (int g32 = 0; g32 < 2; ++g32) {
            // K frags at permuted rows; slot = chunk ^ x7 (2-way, free)
            const int ra = g32 * 32 + rowA;
            const s16x8 kA0 = *(const s16x8*)&Ks[buf][(ra * 8 + (quad ^ x7)) * 8];
            const s16x8 kA1 = *(const s16x8*)&Ks[buf][(ra * 8 + ((4 + quad) ^ x7)) * 8];
            const s16x8 kB0 = *(const s16x8*)&Ks[buf][((ra + 4) * 8 + (quad ^ x7)) * 8];
            const s16x8 kB1 = *(const s16x8*)&Ks[buf][((ra + 4) * 8 + ((4 + quad) ^ x7)) * 8];
            // bias for keys g32*32 + quad*8 + (0..7)
            const f32x4 bA = *(const f32x4*)&biasF[kbase + g32 * 32 + quad * 8];
            const f32x4 bB = *(const f32x4*)&biasF[kbase + g32 * 32 + quad * 8 + 4];
            #pragma unroll
            for (int qg = 0; qg < 2; ++qg) {
                f32x4 Sa = {}, Sb = {};
                Sa = MFMA32(kA0, qf[qg][0], Sa);
                Sa = MFMA32(kA1, qf[qg][1], Sa);
                Sb = MFMA32(kB0, qf[qg][0], Sb);
                Sb = MFMA32(kB1, qf[qg][1], Sb);
                // fixed-max softmax: P = exp2(S + bias)
                #pragma unroll
                for (int r = 0; r < 4; ++r) {
                    Sa[r] = exp2f(Sa[r] + bA[r]);
                    Sb[r] = exp2f(Sb[r] + bB[r]);
                }
                union { s16x8 v; unsigned int u[4]; } pu;
                pu.u[0] = pkbf(Sa[0], Sa[1]);
                pu.u[1] = pkbf(Sa[2], Sa[3]);
                pu.u[2] = pkbf(Sb[0], Sb[1]);
                pu.u[3] = pkbf(Sb[2], Sb[3]);
                pf[qg][g32] = pu.v;
            }
        }

        // ---- O += P @ V ; li += P @ 1 (all MFMA32, P from registers) ----
        #pragma unroll
        for (int g32 = 0; g32 < 2; ++g32) {
            s16x8 vf[4];
            #pragma unroll
            for (int nt = 0; nt < 4; ++nt) {
                const int d = nt * 16 + laneN;
                vf[nt] = *(const s16x8*)&Vs[buf][(d * 8 + ((g32 * 4 + quad) ^ x7)) * 8];
            }
            #pragma unroll
            for (int qg = 0; qg < 2; ++qg) {
                #pragma unroll
                for (int nt = 0; nt < 4; ++nt)
                    O[qg][nt] = MFMA32(pf[qg][g32], vf[nt], O[qg][nt]);
                liacc[qg] = MFMA32(pf[qg][g32], ones, liacc[qg]);
            }
        }
    }

    // ---- epilogue: Out[b,t, h*64+d] bf16 ; li already in O's layout ----
    #pragma unroll
    for (int qg = 0; qg < 2; ++qg) {
        #pragma unroll
        for (int r = 0; r < 4; ++r) {
            const float inv = 1.0f / liacc[qg][r];
            const int tq = qbase + qg * 16 + quad * 4 + r;
            #pragma unroll
            for (int nt = 0; nt < 4; ++nt)
                Out[(size_t)(b * T_ + tq) * D_ + h * HD_ + nt * 16 + laneN] =
                    f2bf(O[qg][nt][r] * inv);
        }
    }
}

extern "C" void kernel_launch(void* const* d_in, const int* in_sizes, int n_in,
                              void* d_out, int out_size, void* d_ws, size_t ws_size,
                              hipStream_t stream) {
    const float* x     = (const float*)d_in[0];
    const int*   mask  = (const int*)d_in[1];
    const float* W_qkv = (const float*)d_in[2];
    const float* b_qkv = (const float*)d_in[3];
    const float* W_out = (const float*)d_in[4];
    const float* b_out = (const float*)d_in[5];
    float* out = (float*)d_out;

    unsigned short* ws = (unsigned short*)d_ws;
    const size_t NX = (size_t)B_ * T_ * D_;          // 8388608
    unsigned short* xb  = ws;                        // x bf16; reused for attn out
    unsigned short* Qb  = xb + NX;
    unsigned short* Kb  = Qb + NX;
    unsigned short* Vtb = Kb + NX;
    unsigned short* Wqt = Vtb + NX;                  // [3D, D]
    unsigned short* Wot = Wqt + (size_t)3 * D_ * D_; // [D, D]
    unsigned short* attn = xb;                       // alias: xb dead after GEMM1

    cast_bf16_kernel<<<(int)(NX / 4 + 255) / 256, 256, 0, stream>>>(x, xb, (int)(NX / 4));
    {
        dim3 blk(32, 8), grd(3 * D_ / 32, D_ / 32);
        transpose_cast_kernel<<<grd, blk, 0, stream>>>(W_qkv, Wqt, D_, 3 * D_);
    }
    {
        dim3 blk(32, 8), grd(D_ / 32, D_ / 32);
        transpose_cast_kernel<<<grd, blk, 0, stream>>>(W_out, Wot, D_, D_);
    }
    gemm_bt_kernel<1><<<dim3(3 * D_ / 128, B_ * T_ / 128), 256, 0, stream>>>(
        xb, Wqt, b_qkv, nullptr, Qb, Kb, Vtb, B_ * T_, 3 * D_, D_);
    attn_kernel<<<dim3(B_ * H_, T_ / 128), 256, 0, stream>>>(Qb, Kb, Vtb, mask, attn);
    gemm_bt_kernel<0><<<dim3(D_ / 128, B_ * T_ / 128), 256, 0, stream>>>(
        attn, Wot, b_out, out, nullptr, nullptr, nullptr, B_ * T_, D_, D_);
}

// Round 5
// 334.337 us; speedup vs baseline: 2.4019x; 1.0647x over previous
//
#include <hip/hip_runtime.h>
#include <hip/hip_bf16.h>
#include <stdint.h>

// ---- problem constants ----
#define B_  4
#define T_  2048
#define D_  1024
#define H_  16
#define HD_ 64

typedef short s16x8 __attribute__((ext_vector_type(8)));
typedef short s16x4 __attribute__((ext_vector_type(4)));
typedef float f32x4 __attribute__((ext_vector_type(4)));

#define MFMA32(a, b, c) __builtin_amdgcn_mfma_f32_16x16x32_bf16(a, b, c, 0, 0, 0)

// raw v_exp_f32 (2^x) without OCML denormal-handling wrapper
#if __has_builtin(__builtin_amdgcn_exp2f)
#define FEXP2(x) __builtin_amdgcn_exp2f(x)
#else
#define FEXP2(x) exp2f(x)
#endif

__device__ __forceinline__ unsigned short f2bf(float f) {
    union { float f; unsigned int u; } v; v.f = f;
    unsigned int r = v.u + 0x7fffu + ((v.u >> 16) & 1u);   // RNE
    return (unsigned short)(r >> 16);
}

__device__ __forceinline__ unsigned int pkbf(float a, float b) {
    __hip_bfloat162 h = __float22bfloat162_rn(float2{a, b});  // v_cvt_pk_bf16_f32
    union { __hip_bfloat162 h; unsigned int u; } v; v.h = h;
    return v.u;
}

__device__ __forceinline__ void async16(const void* g, void* l) {
    __builtin_amdgcn_global_load_lds(
        (const __attribute__((address_space(1))) unsigned int*)g,
        (__attribute__((address_space(3))) unsigned int*)l, 16, 0, 0);
}

// ---------------- cast x (fp32 -> bf16), 4 elems/thread ----------------
__global__ void cast_bf16_kernel(const float* __restrict__ in,
                                 unsigned short* __restrict__ out, int n4) {
    int i = blockIdx.x * 256 + threadIdx.x;
    if (i < n4) {
        float4 v = ((const float4*)in)[i];
        ushort4 o;
        o.x = f2bf(v.x); o.y = f2bf(v.y); o.z = f2bf(v.z); o.w = f2bf(v.w);
        ((ushort4*)out)[i] = o;
    }
}

// ------------- transpose+cast: W[K,N] fp32 -> Wt[N,K] bf16 -------------
__global__ void transpose_cast_kernel(const float* __restrict__ W,
                                      unsigned short* __restrict__ Wt,
                                      int K, int N) {
    __shared__ float t[32][33];
    const int bx = blockIdx.x * 32;   // n
    const int by = blockIdx.y * 32;   // k
    const int tx = threadIdx.x, ty = threadIdx.y;
    #pragma unroll
    for (int j = 0; j < 32; j += 8)
        t[ty + j][tx] = W[(size_t)(by + ty + j) * N + bx + tx];
    __syncthreads();
    #pragma unroll
    for (int j = 0; j < 32; j += 8)
        Wt[(size_t)(bx + ty + j) * K + by + tx] = f2bf(t[tx][ty + j]);
}

// ---------------- bf16 MFMA GEMM: C = A[M,K] @ Bt[N,K]^T + bias --------
// MODE 0: Cf = acc + bias (fp32). MODE 1: QKV scatter; Q pre-scaled by
// 0.125*log2e so attention softmax runs in base-2 with no per-S multiply.
template <int MODE>
__global__ __launch_bounds__(256)
void gemm_bt_kernel(const unsigned short* __restrict__ A,
                    const unsigned short* __restrict__ Bt,
                    const float* __restrict__ bias,
                    float* __restrict__ Cf,
                    unsigned short* __restrict__ Qo,
                    unsigned short* __restrict__ Ko,
                    unsigned short* __restrict__ Vo,
                    int M, int N, int K) {
    __shared__ __align__(16) unsigned short As[128 * 32];
    __shared__ __align__(16) unsigned short Bs[128 * 32];
    const int tid = threadIdx.x;
    const int w = tid >> 6, lane = tid & 63;
    const int laneN = lane & 15, quad = lane >> 4;
    const int rm0 = blockIdx.y * 128, rn0 = blockIdx.x * 128;
    const int wr = (w >> 1) * 64, wc = (w & 1) * 64;

    f32x4 acc[4][4] = {};

    for (int kk = 0; kk < K; kk += 32) {
        #pragma unroll
        for (int i = 0; i < 2; ++i) {
            const int c = (w * 2 + i) * 64 + lane;   // 0..511 chunk id
            const int row = c >> 2, k2 = c & 3;
            async16(A  + (size_t)(rm0 + row) * K + kk + k2 * 8, (char*)As + (size_t)c * 16);
            async16(Bt + (size_t)(rn0 + row) * K + kk + k2 * 8, (char*)Bs + (size_t)c * 16);
        }
        __syncthreads();
        s16x8 av[4], bv[4];
        #pragma unroll
        for (int ms = 0; ms < 4; ++ms)
            av[ms] = *(const s16x8*)&As[(wr + ms * 16 + laneN) * 32 + quad * 8];
        #pragma unroll
        for (int ns = 0; ns < 4; ++ns)
            bv[ns] = *(const s16x8*)&Bs[(wc + ns * 16 + laneN) * 32 + quad * 8];
        #pragma unroll
        for (int ms = 0; ms < 4; ++ms)
            #pragma unroll
            for (int ns = 0; ns < 4; ++ns)
                acc[ms][ns] = MFMA32(av[ms], bv[ns], acc[ms][ns]);
        __syncthreads();
    }

    if (MODE == 0) {
        #pragma unroll
        for (int ms = 0; ms < 4; ++ms) {
            const int gm0 = rm0 + wr + ms * 16 + quad * 4;
            #pragma unroll
            for (int ns = 0; ns < 4; ++ns) {
                const int gn = rn0 + wc + ns * 16 + laneN;
                const float bb = bias[gn];
                #pragma unroll
                for (int r = 0; r < 4; ++r)
                    Cf[(size_t)(gm0 + r) * N + gn] = acc[ms][ns][r] + bb;
            }
        }
    } else {
        const float qscl = 0.125f * 1.44269504088896f;   // 1/sqrt(64)*log2(e)
        #pragma unroll
        for (int ms = 0; ms < 4; ++ms) {
            const int gm0 = rm0 + wr + ms * 16 + quad * 4;
            #pragma unroll
            for (int ns = 0; ns < 4; ++ns) {
                const int gn = rn0 + wc + ns * 16 + laneN;
                const float bb = bias[gn];
                const int s = gn >> 10, rr = gn & 1023, hh = rr >> 6, dd = rr & 63;
                #pragma unroll
                for (int r = 0; r < 4; ++r) {
                    const int gm = gm0 + r;
                    const int bidx = gm >> 11, t = gm & (T_ - 1);
                    float vacc = acc[ms][ns][r] + bb;
                    if (s == 0) vacc *= qscl;
                    const unsigned short val = f2bf(vacc);
                    const int bh = bidx * H_ + hh;
                    if (s == 0)      Qo[((size_t)bh * T_ + t) * HD_ + dd] = val;
                    else if (s == 1) Ko[((size_t)bh * T_ + t) * HD_ + dd] = val;
                    else             Vo[((size_t)bh * HD_ + dd) * T_ + t] = val;
                }
            }
        }
    }
}

// ---------------- flash attention v5 ----------------
// grid(B*H, T/128): all q-blocks of one head land on one XCD -> K/V stay
// L2-resident.  256 thr (4 waves), 32 q-rows/wave.  Fixed-max base-2
// softmax; mask bias enters as the MFMA ACCUMULATOR INIT (zero extra VALU);
// exp is raw v_exp_f32 via __builtin_amdgcn_exp2f (no OCML wrapper).
// S^T computed with PERMUTED K-rows so its C-layout concatenates into the
// 16x16x32 A-operand (k=quad*8+j) -> PV and row-sum (B=ones) run as MFMA32
// straight from registers.  K/V double-buffered in LDS via global_load_lds,
// XOR-swizzled; one barrier/tile.
__global__ __launch_bounds__(256, 4)
void attn_kernel(const unsigned short* __restrict__ Q,
                 const unsigned short* __restrict__ Kb,
                 const unsigned short* __restrict__ VT,
                 const int* __restrict__ mask,
                 unsigned short* __restrict__ Out) {
    __shared__ __align__(16) unsigned short Ks[2][64 * 64];  // [key][d] swizzled
    __shared__ __align__(16) unsigned short Vs[2][64 * 64];  // [d][key] swizzled
    __shared__ float biasF[T_];                              // fp32 mask bias
    const int tid = threadIdx.x;
    const int lane = tid & 63;
    const int w = tid >> 6;
    const int laneN = lane & 15, quad = lane >> 4;
    const int x7 = laneN & 7;
    const int bh = blockIdx.x;
    const int b = bh >> 4, h = bh & 15;
    const int qbase = blockIdx.y * 128 + w * 32;

    for (int i = tid; i < T_; i += 256)
        biasF[i] = mask[b * T_ + i] ? 0.f : -1.0e9f;

    // Q B-operand frags (pre-scaled by 0.125*log2e in GEMM1 epilogue)
    s16x8 qf[2][2];
    #pragma unroll
    for (int qg = 0; qg < 2; ++qg) {
        const size_t qoff = ((size_t)bh * T_ + qbase + qg * 16 + laneN) * HD_ + quad * 8;
        qf[qg][0] = *(const s16x8*)&Q[qoff];
        qf[qg][1] = *(const s16x8*)&Q[qoff + 32];
    }

    s16x8 ones;
    #pragma unroll
    for (int j = 0; j < 8; ++j) ones[j] = (short)0x3F80;   // bf16 1.0

    const size_t kRow0 = (size_t)bh * T_ * HD_;
    const size_t vRow0 = (size_t)bh * HD_ * T_;

    // K swizzle f(row) = (row&3) | (((row>>3)&1)<<2); V swizzle f(d) = d&7
    auto issueTile = [&](int kt, int bufsel) {
        const int kbase = kt * 64;
        #pragma unroll
        for (int i = 0; i < 2; ++i) {
            const int c = i * 256 + tid;                    // 512 K chunks
            const int row = c >> 3, s = c & 7;
            const int fk = (row & 3) | (((row >> 3) & 1) << 2);
            const int g = s ^ fk;
            async16(Kb + kRow0 + (size_t)(kbase + row) * HD_ + g * 8,
                    &Ks[bufsel][c * 8]);
        }
        #pragma unroll
        for (int i = 0; i < 2; ++i) {
            const int c = i * 256 + tid;                    // 512 V chunks
            const int d = c >> 3, s = c & 7, g = s ^ (d & 7);
            async16(VT + vRow0 + (size_t)d * T_ + kbase + g * 8,
                    &Vs[bufsel][c * 8]);
        }
    };

    issueTile(0, 0);

    f32x4 O[2][4] = {};        // [qg][nt]; lane: q=quad*4+r, d=nt*16+laneN
    f32x4 liacc[2] = {};       // [qg]; lane: q=quad*4+r (row-sums via MFMA)

    // permuted K rows: rowA(laneN) covers keys quad*8+r after MFMA
    const int rowA = ((laneN >> 2) << 3) + (laneN & 3);     // +4 -> twin half

    #pragma unroll 2
    for (int kt = 0; kt < T_ / 64; ++kt) {
        const int buf = kt & 1;
        const int kbase = kt * 64;
        __syncthreads();                       // buf ready; buf^1 free
        if (kt + 1 < T_ / 64) issueTile(kt + 1, buf ^ 1);

        s16x8 pf[2][2];        // [qg][g32] A-operand P frags (k=quad*8+j)
        #pragma unroll
        for (int g32 = 0; g32 < 2; ++g32) {
            // K frags at permuted rows; slot = chunk ^ x7 (2-way, free)
            const int ra = g32 * 32 + rowA;
            const s16x8 kA0 = *(const s16x8*)&Ks[buf][(ra * 8 + (quad ^ x7)) * 8];
            const s16x8 kA1 = *(const s16x8*)&Ks[buf][(ra * 8 + ((4 + quad) ^ x7)) * 8];
            const s16x8 kB0 = *(const s16x8*)&Ks[buf][((ra + 4) * 8 + (quad ^ x7)) * 8];
            const s16x8 kB1 = *(const s16x8*)&Ks[buf][((ra + 4) * 8 + ((4 + quad) ^ x7)) * 8];
            // bias for keys g32*32 + quad*8 + (0..7) -> MFMA acc init
            const f32x4 bA = *(const f32x4*)&biasF[kbase + g32 * 32 + quad * 8];
            const f32x4 bB = *(const f32x4*)&biasF[kbase + g32 * 32 + quad * 8 + 4];
            #pragma unroll
            for (int qg = 0; qg < 2; ++qg) {
                f32x4 Sa = bA, Sb = bB;        // bias as accumulator init
                Sa = MFMA32(kA0, qf[qg][0], Sa);
                Sa = MFMA32(kA1, qf[qg][1], Sa);
                Sb = MFMA32(kB0, qf[qg][0], Sb);
                Sb = MFMA32(kB1, qf[qg][1], Sb);
                // fixed-max softmax: P = exp2(S)  (raw v_exp_f32)
                #pragma unroll
                for (int r = 0; r < 4; ++r) {
                    Sa[r] = FEXP2(Sa[r]);
                    Sb[r] = FEXP2(Sb[r]);
                }
                union { s16x8 v; unsigned int u[4]; } pu;
                pu.u[0] = pkbf(Sa[0], Sa[1]);
                pu.u[1] = pkbf(Sa[2], Sa[3]);
                pu.u[2] = pkbf(Sb[0], Sb[1]);
                pu.u[3] = pkbf(Sb[2], Sb[3]);
                pf[qg][g32] = pu.v;
            }
        }

        // ---- O += P @ V ; li += P @ 1 (all MFMA32, P from registers) ----
        #pragma unroll
        for (int g32 = 0; g32 < 2; ++g32) {
            s16x8 vf[4];
            #pragma unroll
            for (int nt = 0; nt < 4; ++nt) {
                const int d = nt * 16 + laneN;
                vf[nt] = *(const s16x8*)&Vs[buf][(d * 8 + ((g32 * 4 + quad) ^ x7)) * 8];
            }
            #pragma unroll
            for (int qg = 0; qg < 2; ++qg) {
                #pragma unroll
                for (int nt = 0; nt < 4; ++nt)
                    O[qg][nt] = MFMA32(pf[qg][g32], vf[nt], O[qg][nt]);
                liacc[qg] = MFMA32(pf[qg][g32], ones, liacc[qg]);
            }
        }
    }

    // ---- epilogue: Out[b,t, h*64+d] bf16 ; li already in O's layout ----
    #pragma unroll
    for (int qg = 0; qg < 2; ++qg) {
        #pragma unroll
        for (int r = 0; r < 4; ++r) {
            const float inv = 1.0f / liacc[qg][r];
            const int tq = qbase + qg * 16 + quad * 4 + r;
            #pragma unroll
            for (int nt = 0; nt < 4; ++nt)
                Out[(size_t)(b * T_ + tq) * D_ + h * HD_ + nt * 16 + laneN] =
                    f2bf(O[qg][nt][r] * inv);
        }
    }
}

extern "C" void kernel_launch(void* const* d_in, const int* in_sizes, int n_in,
                              void* d_out, int out_size, void* d_ws, size_t ws_size,
                              hipStream_t stream) {
    const float* x     = (const float*)d_in[0];
    const int*   mask  = (const int*)d_in[1];
    const float* W_qkv = (const float*)d_in[2];
    const float* b_qkv = (const float*)d_in[3];
    const float* W_out = (const float*)d_in[4];
    const float* b_out = (const float*)d_in[5];
    float* out = (float*)d_out;

    unsigned short* ws = (unsigned short*)d_ws;
    const size_t NX = (size_t)B_ * T_ * D_;          // 8388608
    unsigned short* xb  = ws;                        // x bf16; reused for attn out
    unsigned short* Qb  = xb + NX;
    unsigned short* Kb  = Qb + NX;
    unsigned short* Vtb = Kb + NX;
    unsigned short* Wqt = Vtb + NX;                  // [3D, D]
    unsigned short* Wot = Wqt + (size_t)3 * D_ * D_; // [D, D]
    unsigned short* attn = xb;                       // alias: xb dead after GEMM1

    cast_bf16_kernel<<<(int)(NX / 4 + 255) / 256, 256, 0, stream>>>(x, xb, (int)(NX / 4));
    {
        dim3 blk(32, 8), grd(3 * D_ / 32, D_ / 32);
        transpose_cast_kernel<<<grd, blk, 0, stream>>>(W_qkv, Wqt, D_, 3 * D_);
    }
    {
        dim3 blk(32, 8), grd(D_ / 32, D_ / 32);
        transpose_cast_kernel<<<grd, blk, 0, stream>>>(W_out, Wot, D_, D_);
    }
    gemm_bt_kernel<1><<<dim3(3 * D_ / 128, B_ * T_ / 128), 256, 0, stream>>>(
        xb, Wqt, b_qkv, nullptr, Qb, Kb, Vtb, B_ * T_, 3 * D_, D_);
    attn_kernel<<<dim3(B_ * H_, T_ / 128), 256, 0, stream>>>(Qb, Kb, Vtb, mask, attn);
    gemm_bt_kernel<0><<<dim3(D_ / 128, B_ * T_ / 128), 256, 0, stream>>>(
        attn, Wot, b_out, out, nullptr, nullptr, nullptr, B_ * T_, D_, D_);
}

// Round 6
// 287.874 us; speedup vs baseline: 2.7895x; 1.1614x over previous
//
#include <hip/hip_runtime.h>
#include <hip/hip_bf16.h>
#include <stdint.h>

// ---- problem constants ----
#define B_  4
#define T_  2048
#define D_  1024
#define H_  16
#define HD_ 64

typedef short s16x8 __attribute__((ext_vector_type(8)));
typedef short s16x4 __attribute__((ext_vector_type(4)));
typedef float f32x4 __attribute__((ext_vector_type(4)));

#define MFMA32(a, b, c) __builtin_amdgcn_mfma_f32_16x16x32_bf16(a, b, c, 0, 0, 0)

// raw v_exp_f32 (2^x) without OCML denormal-handling wrapper
#if __has_builtin(__builtin_amdgcn_exp2f)
#define FEXP2(x) __builtin_amdgcn_exp2f(x)
#else
#define FEXP2(x) exp2f(x)
#endif

__device__ __forceinline__ unsigned short f2bf(float f) {
    union { float f; unsigned int u; } v; v.f = f;
    unsigned int r = v.u + 0x7fffu + ((v.u >> 16) & 1u);   // RNE
    return (unsigned short)(r >> 16);
}

__device__ __forceinline__ unsigned int pkbf(float a, float b) {
    __hip_bfloat162 h = __float22bfloat162_rn(float2{a, b});  // v_cvt_pk_bf16_f32
    union { __hip_bfloat162 h; unsigned int u; } v; v.h = h;
    return v.u;
}

__device__ __forceinline__ void async16(const void* g, void* l) {
    __builtin_amdgcn_global_load_lds(
        (const __attribute__((address_space(1))) unsigned int*)g,
        (__attribute__((address_space(3))) unsigned int*)l, 16, 0, 0);
}

// ---------------- cast x (fp32 -> bf16), 4 elems/thread ----------------
__global__ void cast_bf16_kernel(const float* __restrict__ in,
                                 unsigned short* __restrict__ out, int n4) {
    int i = blockIdx.x * 256 + threadIdx.x;
    if (i < n4) {
        float4 v = ((const float4*)in)[i];
        ushort4 o;
        o.x = f2bf(v.x); o.y = f2bf(v.y); o.z = f2bf(v.z); o.w = f2bf(v.w);
        ((ushort4*)out)[i] = o;
    }
}

// ------------- transpose+cast: W[K,N] fp32 -> Wt[N,K] bf16 -------------
__global__ void transpose_cast_kernel(const float* __restrict__ W,
                                      unsigned short* __restrict__ Wt,
                                      int K, int N) {
    __shared__ float t[32][33];
    const int bx = blockIdx.x * 32;   // n
    const int by = blockIdx.y * 32;   // k
    const int tx = threadIdx.x, ty = threadIdx.y;
    #pragma unroll
    for (int j = 0; j < 32; j += 8)
        t[ty + j][tx] = W[(size_t)(by + ty + j) * N + bx + tx];
    __syncthreads();
    #pragma unroll
    for (int j = 0; j < 32; j += 8)
        Wt[(size_t)(bx + ty + j) * K + by + tx] = f2bf(t[tx][ty + j]);
}

// ---------------- bf16 MFMA GEMM: C = A[M,K] @ Bt[N,K]^T + bias --------
// BK=64, XOR-swizzled LDS (slot = chunk ^ (row&7)), grid(m-blocks, n-blocks)
// so linear id is m-fastest -> each XCD owns an L2-resident A row-stripe.
// MODE 0: Cf = acc + bias (fp32). MODE 1: QKV scatter (s block-uniform);
// Q pre-scaled by 0.125*log2e; V written via LDS transpose, coalesced 16B.
template <int MODE>
__global__ __launch_bounds__(256)
void gemm_bt_kernel(const unsigned short* __restrict__ A,
                    const unsigned short* __restrict__ Bt,
                    const float* __restrict__ bias,
                    float* __restrict__ Cf,
                    unsigned short* __restrict__ Qo,
                    unsigned short* __restrict__ Ko,
                    unsigned short* __restrict__ Vo,
                    int M, int N, int K) {
    __shared__ __align__(16) unsigned short SMEM[2 * 128 * 64];  // 32 KB
    unsigned short* As = SMEM;
    unsigned short* Bs = SMEM + 128 * 64;
    const int tid = threadIdx.x;
    const int w = tid >> 6, lane = tid & 63;
    const int laneN = lane & 15, quad = lane >> 4;
    const int rm0 = blockIdx.x * 128;      // m block (x fastest -> XCD stripe)
    const int rn0 = blockIdx.y * 128;      // n block
    const int wr = (w >> 1) * 64, wc = (w & 1) * 64;

    f32x4 acc[4][4] = {};

    for (int kk = 0; kk < K; kk += 64) {
        #pragma unroll
        for (int i = 0; i < 4; ++i) {
            const int c = i * 256 + tid;           // 0..1023 chunk id
            const int row = c >> 3, s = c & 7, g = s ^ (row & 7);
            async16(A + (size_t)(rm0 + row) * K + kk + g * 8,
                    (char*)As + (size_t)c * 16);
        }
        #pragma unroll
        for (int i = 0; i < 4; ++i) {
            const int c = i * 256 + tid;
            const int row = c >> 3, s = c & 7, g = s ^ (row & 7);
            async16(Bt + (size_t)(rn0 + row) * K + kk + g * 8,
                    (char*)Bs + (size_t)c * 16);
        }
        __syncthreads();
        s16x8 av[2][4], bv[2][4];
        #pragma unroll
        for (int h = 0; h < 2; ++h) {
            #pragma unroll
            for (int ms = 0; ms < 4; ++ms) {
                const int row = wr + ms * 16 + laneN;
                av[h][ms] = *(const s16x8*)&As[row * 64 + ((h * 4 + quad) ^ (row & 7)) * 8];
            }
            #pragma unroll
            for (int ns = 0; ns < 4; ++ns) {
                const int row = wc + ns * 16 + laneN;
                bv[h][ns] = *(const s16x8*)&Bs[row * 64 + ((h * 4 + quad) ^ (row & 7)) * 8];
            }
        }
        #pragma unroll
        for (int ms = 0; ms < 4; ++ms)
            #pragma unroll
            for (int ns = 0; ns < 4; ++ns) {
                acc[ms][ns] = MFMA32(av[0][ms], bv[0][ns], acc[ms][ns]);
                acc[ms][ns] = MFMA32(av[1][ms], bv[1][ns], acc[ms][ns]);
            }
        __syncthreads();
    }

    if (MODE == 0) {
        #pragma unroll
        for (int ms = 0; ms < 4; ++ms) {
            const int gm0 = rm0 + wr + ms * 16 + quad * 4;
            #pragma unroll
            for (int ns = 0; ns < 4; ++ns) {
                const int gn = rn0 + wc + ns * 16 + laneN;
                const float bb = bias[gn];
                #pragma unroll
                for (int r = 0; r < 4; ++r)
                    Cf[(size_t)(gm0 + r) * N + gn] = acc[ms][ns][r] + bb;
            }
        }
    } else {
        const int s = rn0 >> 10;                 // 0=Q 1=K 2=V, block-uniform
        const int bidx = rm0 >> 11, t0 = rm0 & (T_ - 1);
        if (s < 2) {
            const float fs = (s == 0) ? 0.125f * 1.44269504088896f : 1.0f;
            unsigned short* P = (s == 0) ? Qo : Ko;
            #pragma unroll
            for (int ms = 0; ms < 4; ++ms) {
                const int lm0 = wr + ms * 16 + quad * 4;
                #pragma unroll
                for (int ns = 0; ns < 4; ++ns) {
                    const int gn = rn0 + wc + ns * 16 + laneN;
                    const float bb = bias[gn];
                    const int rr = gn & 1023, hh = rr >> 6, dd = rr & 63;
                    const size_t base = ((size_t)(bidx * H_ + hh) * T_ + t0);
                    #pragma unroll
                    for (int r = 0; r < 4; ++r)
                        P[(base + lm0 + r) * HD_ + dd] =
                            f2bf((acc[ms][ns][r] + bb) * fs);
                }
            }
        } else {
            // V: acc -> swizzled LDS [n_local][m_local] -> coalesced stores
            #pragma unroll
            for (int ms = 0; ms < 4; ++ms) {
                const int lm0 = wr + ms * 16 + quad * 4;
                #pragma unroll
                for (int ns = 0; ns < 4; ++ns) {
                    const int nl = wc + ns * 16 + laneN;
                    const float bb = bias[rn0 + nl];
                    const int sw = (nl & 7) << 3;
                    #pragma unroll
                    for (int r = 0; r < 4; ++r)
                        SMEM[nl * 128 + ((lm0 + r) ^ sw)] =
                            f2bf(acc[ms][ns][r] + bb);
                }
            }
            __syncthreads();
            const int nl = tid >> 1, half = tid & 1;
            const int hh = nl >> 6, d = nl & 63;
            const int hAbs = bidx * H_ + ((rn0 & 1023) >> 6) + hh;
            unsigned short* rowp = Vo + ((size_t)hAbs * HD_ + d) * T_ + t0;
            const int swz = nl & 7;
            #pragma unroll
            for (int j = 0; j < 8; ++j) {
                const s16x8 vv = *(const s16x8*)&SMEM[nl * 128 + half * 64 + j * 8];
                const int mlog = half * 64 + ((j ^ swz) * 8);
                *(s16x8*)(rowp + mlog) = vv;
            }
        }
    }
}

// ---------------- flash attention v5 ----------------
// grid(B*H, T/128): all q-blocks of one head land on one XCD -> K/V stay
// L2-resident.  256 thr (4 waves), 32 q-rows/wave.  Fixed-max base-2
// softmax; mask bias enters as the MFMA ACCUMULATOR INIT (zero extra VALU);
// exp is raw v_exp_f32.  S^T computed with PERMUTED K-rows so its C-layout
// concatenates into the 16x16x32 A-operand -> PV and row-sum (B=ones) run
// as MFMA32 straight from registers.  K/V double-buffered in LDS via
// global_load_lds, XOR-swizzled; one barrier/tile.
__global__ __launch_bounds__(256, 4)
void attn_kernel(const unsigned short* __restrict__ Q,
                 const unsigned short* __restrict__ Kb,
                 const unsigned short* __restrict__ VT,
                 const int* __restrict__ mask,
                 unsigned short* __restrict__ Out) {
    __shared__ __align__(16) unsigned short Ks[2][64 * 64];  // [key][d] swizzled
    __shared__ __align__(16) unsigned short Vs[2][64 * 64];  // [d][key] swizzled
    __shared__ float biasF[T_];                              // fp32 mask bias
    const int tid = threadIdx.x;
    const int lane = tid & 63;
    const int w = tid >> 6;
    const int laneN = lane & 15, quad = lane >> 4;
    const int x7 = laneN & 7;
    const int bh = blockIdx.x;
    const int b = bh >> 4, h = bh & 15;
    const int qbase = blockIdx.y * 128 + w * 32;

    for (int i = tid; i < T_; i += 256)
        biasF[i] = mask[b * T_ + i] ? 0.f : -1.0e9f;

    // Q B-operand frags (pre-scaled by 0.125*log2e in GEMM1 epilogue)
    s16x8 qf[2][2];
    #pragma unroll
    for (int qg = 0; qg < 2; ++qg) {
        const size_t qoff = ((size_t)bh * T_ + qbase + qg * 16 + laneN) * HD_ + quad * 8;
        qf[qg][0] = *(const s16x8*)&Q[qoff];
        qf[qg][1] = *(const s16x8*)&Q[qoff + 32];
    }

    s16x8 ones;
    #pragma unroll
    for (int j = 0; j < 8; ++j) ones[j] = (short)0x3F80;   // bf16 1.0

    const size_t kRow0 = (size_t)bh * T_ * HD_;
    const size_t vRow0 = (size_t)bh * HD_ * T_;

    // K swizzle f(row) = (row&3) | (((row>>3)&1)<<2); V swizzle f(d) = d&7
    auto issueTile = [&](int kt, int bufsel) {
        const int kbase = kt * 64;
        #pragma unroll
        for (int i = 0; i < 2; ++i) {
            const int c = i * 256 + tid;                    // 512 K chunks
            const int row = c >> 3, s = c & 7;
            const int fk = (row & 3) | (((row >> 3) & 1) << 2);
            const int g = s ^ fk;
            async16(Kb + kRow0 + (size_t)(kbase + row) * HD_ + g * 8,
                    &Ks[bufsel][c * 8]);
        }
        #pragma unroll
        for (int i = 0; i < 2; ++i) {
            const int c = i * 256 + tid;                    // 512 V chunks
            const int d = c >> 3, s = c & 7, g = s ^ (d & 7);
            async16(VT + vRow0 + (size_t)d * T_ + kbase + g * 8,
                    &Vs[bufsel][c * 8]);
        }
    };

    issueTile(0, 0);

    f32x4 O[2][4] = {};        // [qg][nt]; lane: q=quad*4+r, d=nt*16+laneN
    f32x4 liacc[2] = {};       // [qg]; lane: q=quad*4+r (row-sums via MFMA)

    // permuted K rows: rowA(laneN) covers keys quad*8+r after MFMA
    const int rowA = ((laneN >> 2) << 3) + (laneN & 3);     // +4 -> twin half

    #pragma unroll 2
    for (int kt = 0; kt < T_ / 64; ++kt) {
        const int buf = kt & 1;
        const int kbase = kt * 64;
        __syncthreads();                       // buf ready; buf^1 free
        if (kt + 1 < T_ / 64) issueTile(kt + 1, buf ^ 1);

        s16x8 pf[2][2];        // [qg][g32] A-operand P frags (k=quad*8+j)
        #pragma unroll
        for (int g32 = 0; g32 < 2; ++g32) {
            // K frags at permuted rows; slot = chunk ^ x7 (2-way, free)
            const int ra = g32 * 32 + rowA;
            const s16x8 kA0 = *(const s16x8*)&Ks[buf][(ra * 8 + (quad ^ x7)) * 8];
            const s16x8 kA1 = *(const s16x8*)&Ks[buf][(ra * 8 + ((4 + quad) ^ x7)) * 8];
            const s16x8 kB0 = *(const s16x8*)&Ks[buf][((ra + 4) * 8 + (quad ^ x7)) * 8];
            const s16x8 kB1 = *(const s16x8*)&Ks[buf][((ra + 4) * 8 + ((4 + quad) ^ x7)) * 8];
            // bias for keys g32*32 + quad*8 + (0..7) -> MFMA acc init
            const f32x4 bA = *(const f32x4*)&biasF[kbase + g32 * 32 + quad * 8];
            const f32x4 bB = *(const f32x4*)&biasF[kbase + g32 * 32 + quad * 8 + 4];
            #pragma unroll
            for (int qg = 0; qg < 2; ++qg) {
                f32x4 Sa = bA, Sb = bB;        // bias as accumulator init
                Sa = MFMA32(kA0, qf[qg][0], Sa);
                Sa = MFMA32(kA1, qf[qg][1], Sa);
                Sb = MFMA32(kB0, qf[qg][0], Sb);
                Sb = MFMA32(kB1, qf[qg][1], Sb);
                // fixed-max softmax: P = exp2(S)  (raw v_exp_f32)
                #pragma unroll
                for (int r = 0; r < 4; ++r) {
                    Sa[r] = FEXP2(Sa[r]);
                    Sb[r] = FEXP2(Sb[r]);
                }
                union { s16x8 v; unsigned int u[4]; } pu;
                pu.u[0] = pkbf(Sa[0], Sa[1]);
                pu.u[1] = pkbf(Sa[2], Sa[3]);
                pu.u[2] = pkbf(Sb[0], Sb[1]);
                pu.u[3] = pkbf(Sb[2], Sb[3]);
                pf[qg][g32] = pu.v;
            }
        }

        // ---- O += P @ V ; li += P @ 1 (all MFMA32, P from registers) ----
        #pragma unroll
        for (int g32 = 0; g32 < 2; ++g32) {
            s16x8 vf[4];
            #pragma unroll
            for (int nt = 0; nt < 4; ++nt) {
                const int d = nt * 16 + laneN;
                vf[nt] = *(const s16x8*)&Vs[buf][(d * 8 + ((g32 * 4 + quad) ^ x7)) * 8];
            }
            #pragma unroll
            for (int qg = 0; qg < 2; ++qg) {
                #pragma unroll
                for (int nt = 0; nt < 4; ++nt)
                    O[qg][nt] = MFMA32(pf[qg][g32], vf[nt], O[qg][nt]);
                liacc[qg] = MFMA32(pf[qg][g32], ones, liacc[qg]);
            }
        }
    }

    // ---- epilogue: Out[b,t, h*64+d] bf16 ; li already in O's layout ----
    #pragma unroll
    for (int qg = 0; qg < 2; ++qg) {
        #pragma unroll
        for (int r = 0; r < 4; ++r) {
            const float inv = 1.0f / liacc[qg][r];
            const int tq = qbase + qg * 16 + quad * 4 + r;
            #pragma unroll
            for (int nt = 0; nt < 4; ++nt)
                Out[(size_t)(b * T_ + tq) * D_ + h * HD_ + nt * 16 + laneN] =
                    f2bf(O[qg][nt][r] * inv);
        }
    }
}

extern "C" void kernel_launch(void* const* d_in, const int* in_sizes, int n_in,
                              void* d_out, int out_size, void* d_ws, size_t ws_size,
                              hipStream_t stream) {
    const float* x     = (const float*)d_in[0];
    const int*   mask  = (const int*)d_in[1];
    const float* W_qkv = (const float*)d_in[2];
    const float* b_qkv = (const float*)d_in[3];
    const float* W_out = (const float*)d_in[4];
    const float* b_out = (const float*)d_in[5];
    float* out = (float*)d_out;

    unsigned short* ws = (unsigned short*)d_ws;
    const size_t NX = (size_t)B_ * T_ * D_;          // 8388608
    unsigned short* xb  = ws;                        // x bf16; reused for attn out
    unsigned short* Qb  = xb + NX;
    unsigned short* Kb  = Qb + NX;
    unsigned short* Vtb = Kb + NX;
    unsigned short* Wqt = Vtb + NX;                  // [3D, D]
    unsigned short* Wot = Wqt + (size_t)3 * D_ * D_; // [D, D]
    unsigned short* attn = xb;                       // alias: xb dead after GEMM1

    cast_bf16_kernel<<<(int)(NX / 4 + 255) / 256, 256, 0, stream>>>(x, xb, (int)(NX / 4));
    {
        dim3 blk(32, 8), grd(3 * D_ / 32, D_ / 32);
        transpose_cast_kernel<<<grd, blk, 0, stream>>>(W_qkv, Wqt, D_, 3 * D_);
    }
    {
        dim3 blk(32, 8), grd(D_ / 32, D_ / 32);
        transpose_cast_kernel<<<grd, blk, 0, stream>>>(W_out, Wot, D_, D_);
    }
    gemm_bt_kernel<1><<<dim3(B_ * T_ / 128, 3 * D_ / 128), 256, 0, stream>>>(
        xb, Wqt, b_qkv, nullptr, Qb, Kb, Vtb, B_ * T_, 3 * D_, D_);
    attn_kernel<<<dim3(B_ * H_, T_ / 128), 256, 0, stream>>>(Qb, Kb, Vtb, mask, attn);
    gemm_bt_kernel<0><<<dim3(B_ * T_ / 128, D_ / 128), 256, 0, stream>>>(
        attn, Wot, b_out, out, nullptr, nullptr, nullptr, B_ * T_, D_, D_);
}

// Round 7
// 273.089 us; speedup vs baseline: 2.9406x; 1.0541x over previous
//
#include <hip/hip_runtime.h>
#include <hip/hip_bf16.h>
#include <stdint.h>

// ---- problem constants ----
#define B_  4
#define T_  2048
#define D_  1024
#define H_  16
#define HD_ 64

typedef short s16x8 __attribute__((ext_vector_type(8)));
typedef short s16x4 __attribute__((ext_vector_type(4)));
typedef float f32x4 __attribute__((ext_vector_type(4)));

#define MFMA32(a, b, c) __builtin_amdgcn_mfma_f32_16x16x32_bf16(a, b, c, 0, 0, 0)

// raw v_exp_f32 (2^x) without OCML denormal-handling wrapper
#if __has_builtin(__builtin_amdgcn_exp2f)
#define FEXP2(x) __builtin_amdgcn_exp2f(x)
#else
#define FEXP2(x) exp2f(x)
#endif

__device__ __forceinline__ unsigned short f2bf(float f) {
    union { float f; unsigned int u; } v; v.f = f;
    unsigned int r = v.u + 0x7fffu + ((v.u >> 16) & 1u);   // RNE
    return (unsigned short)(r >> 16);
}

__device__ __forceinline__ unsigned int pkbf(float a, float b) {
    __hip_bfloat162 h = __float22bfloat162_rn(float2{a, b});  // v_cvt_pk_bf16_f32
    union { __hip_bfloat162 h; unsigned int u; } v; v.h = h;
    return v.u;
}

__device__ __forceinline__ void async16(const void* g, void* l) {
    __builtin_amdgcn_global_load_lds(
        (const __attribute__((address_space(1))) unsigned int*)g,
        (__attribute__((address_space(3))) unsigned int*)l, 16, 0, 0);
}

// ---------------- cast x (fp32 -> bf16), 4 elems/thread ----------------
__global__ void cast_bf16_kernel(const float* __restrict__ in,
                                 unsigned short* __restrict__ out, int n4) {
    int i = blockIdx.x * 256 + threadIdx.x;
    if (i < n4) {
        float4 v = ((const float4*)in)[i];
        ushort4 o;
        o.x = f2bf(v.x); o.y = f2bf(v.y); o.z = f2bf(v.z); o.w = f2bf(v.w);
        ((ushort4*)out)[i] = o;
    }
}

// ------------- transpose+cast: W[K,N] fp32 -> Wt[N,K] bf16 -------------
__global__ void transpose_cast_kernel(const float* __restrict__ W,
                                      unsigned short* __restrict__ Wt,
                                      int K, int N) {
    __shared__ float t[32][33];
    const int bx = blockIdx.x * 32;   // n
    const int by = blockIdx.y * 32;   // k
    const int tx = threadIdx.x, ty = threadIdx.y;
    #pragma unroll
    for (int j = 0; j < 32; j += 8)
        t[ty + j][tx] = W[(size_t)(by + ty + j) * N + bx + tx];
    __syncthreads();
    #pragma unroll
    for (int j = 0; j < 32; j += 8)
        Wt[(size_t)(bx + ty + j) * K + by + tx] = f2bf(t[tx][ty + j]);
}

// ---------------- bf16 MFMA GEMM: C = A[M,K] @ Bt[N,K]^T + bias --------
// BK=64, XOR-swizzled LDS (slot = chunk ^ (row&7)), grid(m-blocks, n-blocks)
// so linear id is m-fastest -> each XCD owns an L2-resident A row-stripe.
// MODE 0: Cf = acc + bias (fp32). MODE 1: QKV scatter (s block-uniform);
// Q pre-scaled by 0.125*log2e; V written via LDS transpose, coalesced 16B.
template <int MODE>
__global__ __launch_bounds__(256)
void gemm_bt_kernel(const unsigned short* __restrict__ A,
                    const unsigned short* __restrict__ Bt,
                    const float* __restrict__ bias,
                    float* __restrict__ Cf,
                    unsigned short* __restrict__ Qo,
                    unsigned short* __restrict__ Ko,
                    unsigned short* __restrict__ Vo,
                    int M, int N, int K) {
    __shared__ __align__(16) unsigned short SMEM[2 * 128 * 64];  // 32 KB
    unsigned short* As = SMEM;
    unsigned short* Bs = SMEM + 128 * 64;
    const int tid = threadIdx.x;
    const int w = tid >> 6, lane = tid & 63;
    const int laneN = lane & 15, quad = lane >> 4;
    const int rm0 = blockIdx.x * 128;      // m block (x fastest -> XCD stripe)
    const int rn0 = blockIdx.y * 128;      // n block
    const int wr = (w >> 1) * 64, wc = (w & 1) * 64;

    f32x4 acc[4][4] = {};

    for (int kk = 0; kk < K; kk += 64) {
        #pragma unroll
        for (int i = 0; i < 4; ++i) {
            const int c = i * 256 + tid;           // 0..1023 chunk id
            const int row = c >> 3, s = c & 7, g = s ^ (row & 7);
            async16(A + (size_t)(rm0 + row) * K + kk + g * 8,
                    (char*)As + (size_t)c * 16);
        }
        #pragma unroll
        for (int i = 0; i < 4; ++i) {
            const int c = i * 256 + tid;
            const int row = c >> 3, s = c & 7, g = s ^ (row & 7);
            async16(Bt + (size_t)(rn0 + row) * K + kk + g * 8,
                    (char*)Bs + (size_t)c * 16);
        }
        __syncthreads();
        s16x8 av[2][4], bv[2][4];
        #pragma unroll
        for (int h = 0; h < 2; ++h) {
            #pragma unroll
            for (int ms = 0; ms < 4; ++ms) {
                const int row = wr + ms * 16 + laneN;
                av[h][ms] = *(const s16x8*)&As[row * 64 + ((h * 4 + quad) ^ (row & 7)) * 8];
            }
            #pragma unroll
            for (int ns = 0; ns < 4; ++ns) {
                const int row = wc + ns * 16 + laneN;
                bv[h][ns] = *(const s16x8*)&Bs[row * 64 + ((h * 4 + quad) ^ (row & 7)) * 8];
            }
        }
        #pragma unroll
        for (int ms = 0; ms < 4; ++ms)
            #pragma unroll
            for (int ns = 0; ns < 4; ++ns) {
                acc[ms][ns] = MFMA32(av[0][ms], bv[0][ns], acc[ms][ns]);
                acc[ms][ns] = MFMA32(av[1][ms], bv[1][ns], acc[ms][ns]);
            }
        __syncthreads();
    }

    if (MODE == 0) {
        #pragma unroll
        for (int ms = 0; ms < 4; ++ms) {
            const int gm0 = rm0 + wr + ms * 16 + quad * 4;
            #pragma unroll
            for (int ns = 0; ns < 4; ++ns) {
                const int gn = rn0 + wc + ns * 16 + laneN;
                const float bb = bias[gn];
                #pragma unroll
                for (int r = 0; r < 4; ++r)
                    Cf[(size_t)(gm0 + r) * N + gn] = acc[ms][ns][r] + bb;
            }
        }
    } else {
        const int s = rn0 >> 10;                 // 0=Q 1=K 2=V, block-uniform
        const int bidx = rm0 >> 11, t0 = rm0 & (T_ - 1);
        if (s < 2) {
            const float fs = (s == 0) ? 0.125f * 1.44269504088896f : 1.0f;
            unsigned short* P = (s == 0) ? Qo : Ko;
            #pragma unroll
            for (int ms = 0; ms < 4; ++ms) {
                const int lm0 = wr + ms * 16 + quad * 4;
                #pragma unroll
                for (int ns = 0; ns < 4; ++ns) {
                    const int gn = rn0 + wc + ns * 16 + laneN;
                    const float bb = bias[gn];
                    const int rr = gn & 1023, hh = rr >> 6, dd = rr & 63;
                    const size_t base = ((size_t)(bidx * H_ + hh) * T_ + t0);
                    #pragma unroll
                    for (int r = 0; r < 4; ++r)
                        P[(base + lm0 + r) * HD_ + dd] =
                            f2bf((acc[ms][ns][r] + bb) * fs);
                }
            }
        } else {
            // V: acc -> swizzled LDS [n_local][m_local] -> coalesced stores
            #pragma unroll
            for (int ms = 0; ms < 4; ++ms) {
                const int lm0 = wr + ms * 16 + quad * 4;
                #pragma unroll
                for (int ns = 0; ns < 4; ++ns) {
                    const int nl = wc + ns * 16 + laneN;
                    const float bb = bias[rn0 + nl];
                    const int sw = (nl & 7) << 3;
                    #pragma unroll
                    for (int r = 0; r < 4; ++r)
                        SMEM[nl * 128 + ((lm0 + r) ^ sw)] =
                            f2bf(acc[ms][ns][r] + bb);
                }
            }
            __syncthreads();
            const int nl = tid >> 1, half = tid & 1;
            const int hh = nl >> 6, d = nl & 63;
            const int hAbs = bidx * H_ + ((rn0 & 1023) >> 6) + hh;
            unsigned short* rowp = Vo + ((size_t)hAbs * HD_ + d) * T_ + t0;
            const int swz = nl & 7;
            #pragma unroll
            for (int j = 0; j < 8; ++j) {
                const s16x8 vv = *(const s16x8*)&SMEM[nl * 128 + half * 64 + j * 8];
                const int mlog = half * 64 + ((j ^ swz) * 8);
                *(s16x8*)(rowp + mlog) = vv;
            }
        }
    }
}

// ---------------- flash attention v6 ----------------
// grid(B*H, T/256), 512 thr (8 waves), 32 q-rows/wave, 256 q-rows/block.
// All q-blocks of one head land on one XCD -> K/V stay L2-resident.
// 8 waves share each staged K/V tile: staging bytes + barriers per FLOP
// are HALF of the 4-wave version; 2 blocks/CU * 8 waves = 16 waves/CU.
// Fixed-max base-2 softmax; mask bias enters as the MFMA ACCUMULATOR INIT;
// exp is raw v_exp_f32.  S^T computed with PERMUTED K-rows so its C-layout
// concatenates into the 16x16x32 A-operand -> PV and row-sum (B=ones) run
// as MFMA32 straight from registers.  K/V double-buffered in LDS via
// global_load_lds, XOR-swizzled; one barrier/tile.
__global__ __launch_bounds__(512, 4)
void attn_kernel(const unsigned short* __restrict__ Q,
                 const unsigned short* __restrict__ Kb,
                 const unsigned short* __restrict__ VT,
                 const int* __restrict__ mask,
                 unsigned short* __restrict__ Out) {
    __shared__ __align__(16) unsigned short Ks[2][64 * 64];  // [key][d] swizzled
    __shared__ __align__(16) unsigned short Vs[2][64 * 64];  // [d][key] swizzled
    __shared__ float biasF[T_];                              // fp32 mask bias
    const int tid = threadIdx.x;
    const int lane = tid & 63;
    const int w = tid >> 6;                                  // 0..7
    const int laneN = lane & 15, quad = lane >> 4;
    const int x7 = laneN & 7;
    const int bh = blockIdx.x;
    const int b = bh >> 4, h = bh & 15;
    const int qbase = blockIdx.y * 256 + w * 32;

    for (int i = tid; i < T_; i += 512)
        biasF[i] = mask[b * T_ + i] ? 0.f : -1.0e9f;

    // Q B-operand frags (pre-scaled by 0.125*log2e in GEMM1 epilogue)
    s16x8 qf[2][2];
    #pragma unroll
    for (int qg = 0; qg < 2; ++qg) {
        const size_t qoff = ((size_t)bh * T_ + qbase + qg * 16 + laneN) * HD_ + quad * 8;
        qf[qg][0] = *(const s16x8*)&Q[qoff];
        qf[qg][1] = *(const s16x8*)&Q[qoff + 32];
    }

    s16x8 ones;
    #pragma unroll
    for (int j = 0; j < 8; ++j) ones[j] = (short)0x3F80;   // bf16 1.0

    const size_t kRow0 = (size_t)bh * T_ * HD_;
    const size_t vRow0 = (size_t)bh * HD_ * T_;

    // K swizzle f(row) = (row&3) | (((row>>3)&1)<<2); V swizzle f(d) = d&7
    // 512 threads -> exactly one K chunk + one V chunk per thread per tile.
    auto issueTile = [&](int kt, int bufsel) {
        const int kbase = kt * 64;
        {
            const int c = tid;                              // 512 K chunks
            const int row = c >> 3, s = c & 7;
            const int fk = (row & 3) | (((row >> 3) & 1) << 2);
            const int g = s ^ fk;
            async16(Kb + kRow0 + (size_t)(kbase + row) * HD_ + g * 8,
                    &Ks[bufsel][c * 8]);
        }
        {
            const int c = tid;                              // 512 V chunks
            const int d = c >> 3, s = c & 7, g = s ^ (d & 7);
            async16(VT + vRow0 + (size_t)d * T_ + kbase + g * 8,
                    &Vs[bufsel][c * 8]);
        }
    };

    issueTile(0, 0);

    f32x4 O[2][4] = {};        // [qg][nt]; lane: q=quad*4+r, d=nt*16+laneN
    f32x4 liacc[2] = {};       // [qg]; lane: q=quad*4+r (row-sums via MFMA)

    // permuted K rows: rowA(laneN) covers keys quad*8+r after MFMA
    const int rowA = ((laneN >> 2) << 3) + (laneN & 3);     // +4 -> twin half

    #pragma unroll 2
    for (int kt = 0; kt < T_ / 64; ++kt) {
        const int buf = kt & 1;
        const int kbase = kt * 64;
        __syncthreads();                       // buf ready; buf^1 free
        if (kt + 1 < T_ / 64) issueTile(kt + 1, buf ^ 1);

        s16x8 pf[2][2];        // [qg][g32] A-operand P frags (k=quad*8+j)
        #pragma unroll
        for (int g32 = 0; g32 < 2; ++g32) {
            // K frags at permuted rows; slot = chunk ^ x7 (2-way, free)
            const int ra = g32 * 32 + rowA;
            const s16x8 kA0 = *(const s16x8*)&Ks[buf][(ra * 8 + (quad ^ x7)) * 8];
            const s16x8 kA1 = *(const s16x8*)&Ks[buf][(ra * 8 + ((4 + quad) ^ x7)) * 8];
            const s16x8 kB0 = *(const s16x8*)&Ks[buf][((ra + 4) * 8 + (quad ^ x7)) * 8];
            const s16x8 kB1 = *(const s16x8*)&Ks[buf][((ra + 4) * 8 + ((4 + quad) ^ x7)) * 8];
            // bias for keys g32*32 + quad*8 + (0..7) -> MFMA acc init
            const f32x4 bA = *(const f32x4*)&biasF[kbase + g32 * 32 + quad * 8];
            const f32x4 bB = *(const f32x4*)&biasF[kbase + g32 * 32 + quad * 8 + 4];
            #pragma unroll
            for (int qg = 0; qg < 2; ++qg) {
                f32x4 Sa = bA, Sb = bB;        // bias as accumulator init
                Sa = MFMA32(kA0, qf[qg][0], Sa);
                Sa = MFMA32(kA1, qf[qg][1], Sa);
                Sb = MFMA32(kB0, qf[qg][0], Sb);
                Sb = MFMA32(kB1, qf[qg][1], Sb);
                // fixed-max softmax: P = exp2(S)  (raw v_exp_f32)
                #pragma unroll
                for (int r = 0; r < 4; ++r) {
                    Sa[r] = FEXP2(Sa[r]);
                    Sb[r] = FEXP2(Sb[r]);
                }
                union { s16x8 v; unsigned int u[4]; } pu;
                pu.u[0] = pkbf(Sa[0], Sa[1]);
                pu.u[1] = pkbf(Sa[2], Sa[3]);
                pu.u[2] = pkbf(Sb[0], Sb[1]);
                pu.u[3] = pkbf(Sb[2], Sb[3]);
                pf[qg][g32] = pu.v;
            }
        }

        // ---- O += P @ V ; li += P @ 1 (all MFMA32, P from registers) ----
        #pragma unroll
        for (int g32 = 0; g32 < 2; ++g32) {
            s16x8 vf[4];
            #pragma unroll
            for (int nt = 0; nt < 4; ++nt) {
                const int d = nt * 16 + laneN;
                vf[nt] = *(const s16x8*)&Vs[buf][(d * 8 + ((g32 * 4 + quad) ^ x7)) * 8];
            }
            #pragma unroll
            for (int qg = 0; qg < 2; ++qg) {
                #pragma unroll
                for (int nt = 0; nt < 4; ++nt)
                    O[qg][nt] = MFMA32(pf[qg][g32], vf[nt], O[qg][nt]);
                liacc[qg] = MFMA32(pf[qg][g32], ones, liacc[qg]);
            }
        }
    }

    // ---- epilogue: Out[b,t, h*64+d] bf16 ; li already in O's layout ----
    #pragma unroll
    for (int qg = 0; qg < 2; ++qg) {
        #pragma unroll
        for (int r = 0; r < 4; ++r) {
            const float inv = 1.0f / liacc[qg][r];
            const int tq = qbase + qg * 16 + quad * 4 + r;
            #pragma unroll
            for (int nt = 0; nt < 4; ++nt)
                Out[(size_t)(b * T_ + tq) * D_ + h * HD_ + nt * 16 + laneN] =
                    f2bf(O[qg][nt][r] * inv);
        }
    }
}

extern "C" void kernel_launch(void* const* d_in, const int* in_sizes, int n_in,
                              void* d_out, int out_size, void* d_ws, size_t ws_size,
                              hipStream_t stream) {
    const float* x     = (const float*)d_in[0];
    const int*   mask  = (const int*)d_in[1];
    const float* W_qkv = (const float*)d_in[2];
    const float* b_qkv = (const float*)d_in[3];
    const float* W_out = (const float*)d_in[4];
    const float* b_out = (const float*)d_in[5];
    float* out = (float*)d_out;

    unsigned short* ws = (unsigned short*)d_ws;
    const size_t NX = (size_t)B_ * T_ * D_;          // 8388608
    unsigned short* xb  = ws;                        // x bf16; reused for attn out
    unsigned short* Qb  = xb + NX;
    unsigned short* Kb  = Qb + NX;
    unsigned short* Vtb = Kb + NX;
    unsigned short* Wqt = Vtb + NX;                  // [3D, D]
    unsigned short* Wot = Wqt + (size_t)3 * D_ * D_; // [D, D]
    unsigned short* attn = xb;                       // alias: xb dead after GEMM1

    cast_bf16_kernel<<<(int)(NX / 4 + 255) / 256, 256, 0, stream>>>(x, xb, (int)(NX / 4));
    {
        dim3 blk(32, 8), grd(3 * D_ / 32, D_ / 32);
        transpose_cast_kernel<<<grd, blk, 0, stream>>>(W_qkv, Wqt, D_, 3 * D_);
    }
    {
        dim3 blk(32, 8), grd(D_ / 32, D_ / 32);
        transpose_cast_kernel<<<grd, blk, 0, stream>>>(W_out, Wot, D_, D_);
    }
    gemm_bt_kernel<1><<<dim3(B_ * T_ / 128, 3 * D_ / 128), 256, 0, stream>>>(
        xb, Wqt, b_qkv, nullptr, Qb, Kb, Vtb, B_ * T_, 3 * D_, D_);
    attn_kernel<<<dim3(B_ * H_, T_ / 256), 512, 0, stream>>>(Qb, Kb, Vtb, mask, attn);
    gemm_bt_kernel<0><<<dim3(B_ * T_ / 128, D_ / 128), 256, 0, stream>>>(
        attn, Wot, b_out, out, nullptr, nullptr, nullptr, B_ * T_, D_, D_);
}

// Round 8
// 271.162 us; speedup vs baseline: 2.9614x; 1.0071x over previous
//
#include <hip/hip_runtime.h>
#include <hip/hip_bf16.h>
#include <stdint.h>

// ---- problem constants ----
#define B_  4
#define T_  2048
#define D_  1024
#define H_  16
#define HD_ 64

typedef short s16x8 __attribute__((ext_vector_type(8)));
typedef short s16x4 __attribute__((ext_vector_type(4)));
typedef float f32x4 __attribute__((ext_vector_type(4)));

#define MFMA32(a, b, c) __builtin_amdgcn_mfma_f32_16x16x32_bf16(a, b, c, 0, 0, 0)

// raw v_exp_f32 (2^x) without OCML denormal-handling wrapper
#if __has_builtin(__builtin_amdgcn_exp2f)
#define FEXP2(x) __builtin_amdgcn_exp2f(x)
#else
#define FEXP2(x) exp2f(x)
#endif

__device__ __forceinline__ unsigned short f2bf(float f) {
    union { float f; unsigned int u; } v; v.f = f;
    unsigned int r = v.u + 0x7fffu + ((v.u >> 16) & 1u);   // RNE
    return (unsigned short)(r >> 16);
}

__device__ __forceinline__ unsigned int pkbf(float a, float b) {
    __hip_bfloat162 h = __float22bfloat162_rn(float2{a, b});  // v_cvt_pk_bf16_f32
    union { __hip_bfloat162 h; unsigned int u; } v; v.h = h;
    return v.u;
}

__device__ __forceinline__ void async16(const void* g, void* l) {
    __builtin_amdgcn_global_load_lds(
        (const __attribute__((address_space(1))) unsigned int*)g,
        (__attribute__((address_space(3))) unsigned int*)l, 16, 0, 0);
}

// -------- fused prep: cast x -> bf16  +  transpose-cast both weights -----
// blocks [0, 8192):        cast x (4 elems/thread)
// blocks [8192, 11264):    W_qkv [1024,3072] -> Wqt [3072,1024]
// blocks [11264, 12288):   W_out [1024,1024] -> Wot [1024,1024]
__global__ __launch_bounds__(256)
void prep_kernel(const float* __restrict__ x, unsigned short* __restrict__ xb,
                 const float* __restrict__ Wq, unsigned short* __restrict__ Wqt,
                 const float* __restrict__ Wo, unsigned short* __restrict__ Wot) {
    const int blk = blockIdx.x;
    const int tid = threadIdx.x;
    if (blk < 8192) {
        const int i = blk * 256 + tid;          // n4 = 2097152
        float4 v = ((const float4*)x)[i];
        ushort4 o;
        o.x = f2bf(v.x); o.y = f2bf(v.y); o.z = f2bf(v.z); o.w = f2bf(v.w);
        ((ushort4*)xb)[i] = o;
        return;
    }
    __shared__ float t[32][33];
    const float* W; unsigned short* Wt; int K, N, bx, by;
    if (blk < 11264) {
        const int idx = blk - 8192;             // 96 x 32
        W = Wq; Wt = Wqt; K = 1024; N = 3072;
        bx = (idx % 96) * 32; by = (idx / 96) * 32;
    } else {
        const int idx = blk - 11264;            // 32 x 32
        W = Wo; Wt = Wot; K = 1024; N = 1024;
        bx = (idx % 32) * 32; by = (idx / 32) * 32;
    }
    const int tx = tid & 31, ty = tid >> 5;
    #pragma unroll
    for (int j = 0; j < 32; j += 8)
        t[ty + j][tx] = W[(size_t)(by + ty + j) * N + bx + tx];
    __syncthreads();
    #pragma unroll
    for (int j = 0; j < 32; j += 8)
        Wt[(size_t)(bx + ty + j) * K + by + tx] = f2bf(t[tx][ty + j]);
}

// ---------------- bf16 MFMA GEMM: C = A[M,K] @ Bt[N,K]^T + bias --------
// BK=64, XOR-swizzled LDS (slot = chunk ^ (row&7)), grid(m-blocks, n-blocks)
// so linear id is m-fastest -> each XCD owns an L2-resident A row-stripe.
// MODE 0: Cf = acc + bias (fp32). MODE 1: QKV scatter (s block-uniform);
// Q pre-scaled by 0.125*log2e; V written via LDS transpose, coalesced 16B.
template <int MODE>
__global__ __launch_bounds__(256)
void gemm_bt_kernel(const unsigned short* __restrict__ A,
                    const unsigned short* __restrict__ Bt,
                    const float* __restrict__ bias,
                    float* __restrict__ Cf,
                    unsigned short* __restrict__ Qo,
                    unsigned short* __restrict__ Ko,
                    unsigned short* __restrict__ Vo,
                    int M, int N, int K) {
    __shared__ __align__(16) unsigned short SMEM[2 * 128 * 64];  // 32 KB
    unsigned short* As = SMEM;
    unsigned short* Bs = SMEM + 128 * 64;
    const int tid = threadIdx.x;
    const int w = tid >> 6, lane = tid & 63;
    const int laneN = lane & 15, quad = lane >> 4;
    const int rm0 = blockIdx.x * 128;      // m block (x fastest -> XCD stripe)
    const int rn0 = blockIdx.y * 128;      // n block
    const int wr = (w >> 1) * 64, wc = (w & 1) * 64;

    f32x4 acc[4][4] = {};

    for (int kk = 0; kk < K; kk += 64) {
        #pragma unroll
        for (int i = 0; i < 4; ++i) {
            const int c = i * 256 + tid;           // 0..1023 chunk id
            const int row = c >> 3, s = c & 7, g = s ^ (row & 7);
            async16(A + (size_t)(rm0 + row) * K + kk + g * 8,
                    (char*)As + (size_t)c * 16);
        }
        #pragma unroll
        for (int i = 0; i < 4; ++i) {
            const int c = i * 256 + tid;
            const int row = c >> 3, s = c & 7, g = s ^ (row & 7);
            async16(Bt + (size_t)(rn0 + row) * K + kk + g * 8,
                    (char*)Bs + (size_t)c * 16);
        }
        __syncthreads();
        s16x8 av[2][4], bv[2][4];
        #pragma unroll
        for (int h = 0; h < 2; ++h) {
            #pragma unroll
            for (int ms = 0; ms < 4; ++ms) {
                const int row = wr + ms * 16 + laneN;
                av[h][ms] = *(const s16x8*)&As[row * 64 + ((h * 4 + quad) ^ (row & 7)) * 8];
            }
            #pragma unroll
            for (int ns = 0; ns < 4; ++ns) {
                const int row = wc + ns * 16 + laneN;
                bv[h][ns] = *(const s16x8*)&Bs[row * 64 + ((h * 4 + quad) ^ (row & 7)) * 8];
            }
        }
        #pragma unroll
        for (int ms = 0; ms < 4; ++ms)
            #pragma unroll
            for (int ns = 0; ns < 4; ++ns) {
                acc[ms][ns] = MFMA32(av[0][ms], bv[0][ns], acc[ms][ns]);
                acc[ms][ns] = MFMA32(av[1][ms], bv[1][ns], acc[ms][ns]);
            }
        __syncthreads();
    }

    if (MODE == 0) {
        #pragma unroll
        for (int ms = 0; ms < 4; ++ms) {
            const int gm0 = rm0 + wr + ms * 16 + quad * 4;
            #pragma unroll
            for (int ns = 0; ns < 4; ++ns) {
                const int gn = rn0 + wc + ns * 16 + laneN;
                const float bb = bias[gn];
                #pragma unroll
                for (int r = 0; r < 4; ++r)
                    Cf[(size_t)(gm0 + r) * N + gn] = acc[ms][ns][r] + bb;
            }
        }
    } else {
        const int s = rn0 >> 10;                 // 0=Q 1=K 2=V, block-uniform
        const int bidx = rm0 >> 11, t0 = rm0 & (T_ - 1);
        if (s < 2) {
            const float fs = (s == 0) ? 0.125f * 1.44269504088896f : 1.0f;
            unsigned short* P = (s == 0) ? Qo : Ko;
            #pragma unroll
            for (int ms = 0; ms < 4; ++ms) {
                const int lm0 = wr + ms * 16 + quad * 4;
                #pragma unroll
                for (int ns = 0; ns < 4; ++ns) {
                    const int gn = rn0 + wc + ns * 16 + laneN;
                    const float bb = bias[gn];
                    const int rr = gn & 1023, hh = rr >> 6, dd = rr & 63;
                    const size_t base = ((size_t)(bidx * H_ + hh) * T_ + t0);
                    #pragma unroll
                    for (int r = 0; r < 4; ++r)
                        P[(base + lm0 + r) * HD_ + dd] =
                            f2bf((acc[ms][ns][r] + bb) * fs);
                }
            }
        } else {
            // V: acc -> swizzled LDS [n_local][m_local] -> coalesced stores
            #pragma unroll
            for (int ms = 0; ms < 4; ++ms) {
                const int lm0 = wr + ms * 16 + quad * 4;
                #pragma unroll
                for (int ns = 0; ns < 4; ++ns) {
                    const int nl = wc + ns * 16 + laneN;
                    const float bb = bias[rn0 + nl];
                    const int sw = (nl & 7) << 3;
                    #pragma unroll
                    for (int r = 0; r < 4; ++r)
                        SMEM[nl * 128 + ((lm0 + r) ^ sw)] =
                            f2bf(acc[ms][ns][r] + bb);
                }
            }
            __syncthreads();
            const int nl = tid >> 1, half = tid & 1;
            const int hh = nl >> 6, d = nl & 63;
            const int hAbs = bidx * H_ + ((rn0 & 1023) >> 6) + hh;
            unsigned short* rowp = Vo + ((size_t)hAbs * HD_ + d) * T_ + t0;
            const int swz = nl & 7;
            #pragma unroll
            for (int j = 0; j < 8; ++j) {
                const s16x8 vv = *(const s16x8*)&SMEM[nl * 128 + half * 64 + j * 8];
                const int mlog = half * 64 + ((j ^ swz) * 8);
                *(s16x8*)(rowp + mlog) = vv;
            }
        }
    }
}

// ---------------- flash attention v7: 128-key tiles ----------------
// grid(B*H, T/256), 512 thr (8 waves), 32 q-rows/wave, 256 q-rows/block.
// All q-blocks of one head land on one XCD -> K/V stay L2-resident.
// 128-key K/V tiles double-buffered (72 KB LDS, still 2 blocks/CU):
// barriers per block 32 -> 16, each covering 2x MFMA work.
// Fixed-max base-2 softmax; mask bias enters as the MFMA ACCUMULATOR INIT;
// exp is raw v_exp_f32.  S^T computed with PERMUTED K-rows so its C-layout
// concatenates into the 16x16x32 A-operand -> PV and row-sum (B=ones) run
// as MFMA32 straight from registers; P consumed per 32-key group to cap
// register liveness.
__global__ __launch_bounds__(512, 4)
void attn_kernel(const unsigned short* __restrict__ Q,
                 const unsigned short* __restrict__ Kb,
                 const unsigned short* __restrict__ VT,
                 const int* __restrict__ mask,
                 unsigned short* __restrict__ Out) {
    __shared__ __align__(16) unsigned short Ks[2][128 * 64];  // [key][d] swizzled
    __shared__ __align__(16) unsigned short Vs[2][64 * 128];  // [d][key] swizzled
    __shared__ float biasF[T_];                               // fp32 mask bias
    const int tid = threadIdx.x;
    const int lane = tid & 63;
    const int laneN = lane & 15, quad = lane >> 4;
    const int x7 = laneN & 7;
    const int bh = blockIdx.x;
    const int b = bh >> 4, h = bh & 15;
    const int qbase = blockIdx.y * 256 + (tid >> 6) * 32;

    for (int i = tid; i < T_; i += 512)
        biasF[i] = mask[b * T_ + i] ? 0.f : -1.0e9f;

    // Q B-operand frags (pre-scaled by 0.125*log2e in GEMM1 epilogue)
    s16x8 qf[2][2];
    #pragma unroll
    for (int qg = 0; qg < 2; ++qg) {
        const size_t qoff = ((size_t)bh * T_ + qbase + qg * 16 + laneN) * HD_ + quad * 8;
        qf[qg][0] = *(const s16x8*)&Q[qoff];
        qf[qg][1] = *(const s16x8*)&Q[qoff + 32];
    }

    s16x8 ones;
    #pragma unroll
    for (int j = 0; j < 8; ++j) ones[j] = (short)0x3F80;   // bf16 1.0

    const size_t kRow0 = (size_t)bh * T_ * HD_;
    const size_t vRow0 = (size_t)bh * HD_ * T_;

    // K swizzle f(row) = (row&3)|(((row>>3)&1)<<2) over 8 slots;
    // V swizzle f(d) = d&15 over 16 slots (row stride 256 B).
    auto issueTile = [&](int kt, int bufsel) {
        const int kbase = kt * 128;
        #pragma unroll
        for (int i = 0; i < 2; ++i) {
            const int c = i * 512 + tid;                    // 1024 K chunks
            const int row = c >> 3, s = c & 7;
            const int fk = (row & 3) | (((row >> 3) & 1) << 2);
            const int g = s ^ fk;
            async16(Kb + kRow0 + (size_t)(kbase + row) * HD_ + g * 8,
                    &Ks[bufsel][c * 8]);
        }
        #pragma unroll
        for (int i = 0; i < 2; ++i) {
            const int c = i * 512 + tid;                    // 1024 V chunks
            const int d = c >> 4, s = c & 15, g = s ^ (d & 15);
            async16(VT + vRow0 + (size_t)d * T_ + kbase + g * 8,
                    &Vs[bufsel][c * 8]);
        }
    };

    issueTile(0, 0);

    f32x4 O[2][4] = {};        // [qg][nt]; lane: q=quad*4+r, d=nt*16+laneN
    f32x4 liacc[2] = {};       // [qg]; lane: q=quad*4+r (row-sums via MFMA)

    // permuted K rows: rowA(laneN) covers keys quad*8+r after MFMA
    const int rowA = ((laneN >> 2) << 3) + (laneN & 3);     // +4 -> twin half

    #pragma unroll 2
    for (int kt = 0; kt < T_ / 128; ++kt) {
        const int buf = kt & 1;
        const int kbase = kt * 128;
        __syncthreads();                       // buf ready; buf^1 free
        if (kt + 1 < T_ / 128) issueTile(kt + 1, buf ^ 1);

        #pragma unroll
        for (int g32 = 0; g32 < 4; ++g32) {    // 4 groups of 32 keys
            // ---- S^T for this group (K frags at permuted rows) ----
            const int ra = g32 * 32 + rowA;
            const s16x8 kA0 = *(const s16x8*)&Ks[buf][(ra * 8 + (quad ^ x7)) * 8];
            const s16x8 kA1 = *(const s16x8*)&Ks[buf][(ra * 8 + ((4 + quad) ^ x7)) * 8];
            const s16x8 kB0 = *(const s16x8*)&Ks[buf][((ra + 4) * 8 + (quad ^ x7)) * 8];
            const s16x8 kB1 = *(const s16x8*)&Ks[buf][((ra + 4) * 8 + ((4 + quad) ^ x7)) * 8];
            const f32x4 bA = *(const f32x4*)&biasF[kbase + g32 * 32 + quad * 8];
            const f32x4 bB = *(const f32x4*)&biasF[kbase + g32 * 32 + quad * 8 + 4];
            s16x8 pf[2];
            #pragma unroll
            for (int qg = 0; qg < 2; ++qg) {
                f32x4 Sa = bA, Sb = bB;        // bias as accumulator init
                Sa = MFMA32(kA0, qf[qg][0], Sa);
                Sa = MFMA32(kA1, qf[qg][1], Sa);
                Sb = MFMA32(kB0, qf[qg][0], Sb);
                Sb = MFMA32(kB1, qf[qg][1], Sb);
                #pragma unroll
                for (int r = 0; r < 4; ++r) {
                    Sa[r] = FEXP2(Sa[r]);
                    Sb[r] = FEXP2(Sb[r]);
                }
                union { s16x8 v; unsigned int u[4]; } pu;
                pu.u[0] = pkbf(Sa[0], Sa[1]);
                pu.u[1] = pkbf(Sa[2], Sa[3]);
                pu.u[2] = pkbf(Sb[0], Sb[1]);
                pu.u[3] = pkbf(Sb[2], Sb[3]);
                pf[qg] = pu.v;
            }
            // ---- O += P @ V ; li += P @ 1 (immediate consume) ----
            s16x8 vf[4];
            #pragma unroll
            for (int nt = 0; nt < 4; ++nt) {
                const int d = nt * 16 + laneN;
                const int slog = g32 * 4 + quad;            // logical chunk
                vf[nt] = *(const s16x8*)&Vs[buf][(d * 16 + (slog ^ (d & 15))) * 8];
            }
            #pragma unroll
            for (int qg = 0; qg < 2; ++qg) {
                #pragma unroll
                for (int nt = 0; nt < 4; ++nt)
                    O[qg][nt] = MFMA32(pf[qg], vf[nt], O[qg][nt]);
                liacc[qg] = MFMA32(pf[qg], ones, liacc[qg]);
            }
        }
    }

    // ---- epilogue: Out[b,t, h*64+d] bf16 ; li already in O's layout ----
    #pragma unroll
    for (int qg = 0; qg < 2; ++qg) {
        #pragma unroll
        for (int r = 0; r < 4; ++r) {
            const float inv = 1.0f / liacc[qg][r];
            const int tq = qbase + qg * 16 + quad * 4 + r;
            #pragma unroll
            for (int nt = 0; nt < 4; ++nt)
                Out[(size_t)(b * T_ + tq) * D_ + h * HD_ + nt * 16 + laneN] =
                    f2bf(O[qg][nt][r] * inv);
        }
    }
}

extern "C" void kernel_launch(void* const* d_in, const int* in_sizes, int n_in,
                              void* d_out, int out_size, void* d_ws, size_t ws_size,
                              hipStream_t stream) {
    const float* x     = (const float*)d_in[0];
    const int*   mask  = (const int*)d_in[1];
    const float* W_qkv = (const float*)d_in[2];
    const float* b_qkv = (const float*)d_in[3];
    const float* W_out = (const float*)d_in[4];
    const float* b_out = (const float*)d_in[5];
    float* out = (float*)d_out;

    unsigned short* ws = (unsigned short*)d_ws;
    const size_t NX = (size_t)B_ * T_ * D_;          // 8388608
    unsigned short* xb  = ws;                        // x bf16; reused for attn out
    unsigned short* Qb  = xb + NX;
    unsigned short* Kb  = Qb + NX;
    unsigned short* Vtb = Kb + NX;
    unsigned short* Wqt = Vtb + NX;                  // [3D, D]
    unsigned short* Wot = Wqt + (size_t)3 * D_ * D_; // [D, D]
    unsigned short* attn = xb;                       // alias: xb dead after GEMM1

    prep_kernel<<<12288, 256, 0, stream>>>(x, xb, W_qkv, Wqt, W_out, Wot);
    gemm_bt_kernel<1><<<dim3(B_ * T_ / 128, 3 * D_ / 128), 256, 0, stream>>>(
        xb, Wqt, b_qkv, nullptr, Qb, Kb, Vtb, B_ * T_, 3 * D_, D_);
    attn_kernel<<<dim3(B_ * H_, T_ / 256), 512, 0, stream>>>(Qb, Kb, Vtb, mask, attn);
    gemm_bt_kernel<0><<<dim3(B_ * T_ / 128, D_ / 128), 256, 0, stream>>>(
        attn, Wot, b_out, out, nullptr, nullptr, nullptr, B_ * T_, D_, D_);
}

// Round 9
// 257.498 us; speedup vs baseline: 3.1186x; 1.0531x over previous
//
#include <hip/hip_runtime.h>
#include <hip/hip_bf16.h>
#include <stdint.h>

// ---- problem constants ----
#define B_  4
#define T_  2048
#define D_  1024
#define H_  16
#define HD_ 64

typedef short s16x8 __attribute__((ext_vector_type(8)));
typedef short s16x4 __attribute__((ext_vector_type(4)));
typedef float f32x4 __attribute__((ext_vector_type(4)));

#define MFMA32(a, b, c) __builtin_amdgcn_mfma_f32_16x16x32_bf16(a, b, c, 0, 0, 0)

// raw v_exp_f32 (2^x) without OCML denormal-handling wrapper
#if __has_builtin(__builtin_amdgcn_exp2f)
#define FEXP2(x) __builtin_amdgcn_exp2f(x)
#else
#define FEXP2(x) exp2f(x)
#endif

__device__ __forceinline__ unsigned short f2bf(float f) {
    union { float f; unsigned int u; } v; v.f = f;
    unsigned int r = v.u + 0x7fffu + ((v.u >> 16) & 1u);   // RNE
    return (unsigned short)(r >> 16);
}

__device__ __forceinline__ unsigned int pkbf(float a, float b) {
    __hip_bfloat162 h = __float22bfloat162_rn(float2{a, b});  // v_cvt_pk_bf16_f32
    union { __hip_bfloat162 h; unsigned int u; } v; v.h = h;
    return v.u;
}

__device__ __forceinline__ void async16(const void* g, void* l) {
    __builtin_amdgcn_global_load_lds(
        (const __attribute__((address_space(1))) unsigned int*)g,
        (__attribute__((address_space(3))) unsigned int*)l, 16, 0, 0);
}

// -------- fused prep: cast x -> bf16  +  transpose-cast both weights -----
// blocks [0, 8192):        cast x (4 elems/thread)
// blocks [8192, 11264):    W_qkv [1024,3072] -> Wqt [3072,1024]
// blocks [11264, 12288):   W_out [1024,1024] -> Wot [1024,1024]
__global__ __launch_bounds__(256)
void prep_kernel(const float* __restrict__ x, unsigned short* __restrict__ xb,
                 const float* __restrict__ Wq, unsigned short* __restrict__ Wqt,
                 const float* __restrict__ Wo, unsigned short* __restrict__ Wot) {
    const int blk = blockIdx.x;
    const int tid = threadIdx.x;
    if (blk < 8192) {
        const int i = blk * 256 + tid;          // n4 = 2097152
        float4 v = ((const float4*)x)[i];
        ushort4 o;
        o.x = f2bf(v.x); o.y = f2bf(v.y); o.z = f2bf(v.z); o.w = f2bf(v.w);
        ((ushort4*)xb)[i] = o;
        return;
    }
    __shared__ float t[32][33];
    const float* W; unsigned short* Wt; int K, N, bx, by;
    if (blk < 11264) {
        const int idx = blk - 8192;             // 96 x 32
        W = Wq; Wt = Wqt; K = 1024; N = 3072;
        bx = (idx % 96) * 32; by = (idx / 96) * 32;
    } else {
        const int idx = blk - 11264;            // 32 x 32
        W = Wo; Wt = Wot; K = 1024; N = 1024;
        bx = (idx % 32) * 32; by = (idx / 32) * 32;
    }
    const int tx = tid & 31, ty = tid >> 5;
    #pragma unroll
    for (int j = 0; j < 32; j += 8)
        t[ty + j][tx] = W[(size_t)(by + ty + j) * N + bx + tx];
    __syncthreads();
    #pragma unroll
    for (int j = 0; j < 32; j += 8)
        Wt[(size_t)(bx + ty + j) * K + by + tx] = f2bf(t[tx][ty + j]);
}

// ---------------- bf16 MFMA GEMM: C = A[M,K] @ Bt[N,K]^T + bias --------
// BK=64, DOUBLE-BUFFERED 64 KB LDS, ONE barrier per K-iter: prefetch of
// tile k+1 issues before the MFMA burst of tile k, so the global->LDS
// latency overlaps compute and the barrier's vmcnt drain is pre-hidden.
// XOR-swizzled LDS (slot = chunk ^ (row&7)); grid(m-blocks, n-blocks) so
// linear id is m-fastest -> each XCD owns an L2-resident A row-stripe.
// MODE 0: Cf = acc + bias (fp32). MODE 1: QKV scatter (s block-uniform);
// Q pre-scaled by 0.125*log2e; V written via LDS transpose, coalesced 16B.
template <int MODE>
__global__ __launch_bounds__(256)
void gemm_bt_kernel(const unsigned short* __restrict__ A,
                    const unsigned short* __restrict__ Bt,
                    const float* __restrict__ bias,
                    float* __restrict__ Cf,
                    unsigned short* __restrict__ Qo,
                    unsigned short* __restrict__ Ko,
                    unsigned short* __restrict__ Vo,
                    int M, int N, int K) {
    __shared__ __align__(16) unsigned short SMEM[4 * 128 * 64];  // 64 KB
    const int tid = threadIdx.x;
    const int w = tid >> 6, lane = tid & 63;
    const int laneN = lane & 15, quad = lane >> 4;
    const int rm0 = blockIdx.x * 128;      // m block (x fastest -> XCD stripe)
    const int rn0 = blockIdx.y * 128;      // n block
    const int wr = (w >> 1) * 64, wc = (w & 1) * 64;

    f32x4 acc[4][4] = {};

    auto issueG = [&](int kk, int bufsel) {
        unsigned short* As = SMEM + bufsel * 8192;
        unsigned short* Bs = SMEM + 16384 + bufsel * 8192;
        #pragma unroll
        for (int i = 0; i < 4; ++i) {
            const int c = i * 256 + tid;           // 0..1023 chunk id
            const int row = c >> 3, s = c & 7, g = s ^ (row & 7);
            async16(A + (size_t)(rm0 + row) * K + kk + g * 8,
                    (char*)As + (size_t)c * 16);
        }
        #pragma unroll
        for (int i = 0; i < 4; ++i) {
            const int c = i * 256 + tid;
            const int row = c >> 3, s = c & 7, g = s ^ (row & 7);
            async16(Bt + (size_t)(rn0 + row) * K + kk + g * 8,
                    (char*)Bs + (size_t)c * 16);
        }
    };

    issueG(0, 0);
    const int KI = K >> 6;                 // 16 iters at K=1024
    for (int it = 0; it < KI; ++it) {
        const int buf = it & 1;
        __syncthreads();                   // tile it ready; buf^1 reads done
        const unsigned short* As = SMEM + buf * 8192;
        const unsigned short* Bs = SMEM + 16384 + buf * 8192;
        s16x8 av[2][4], bv[2][4];
        #pragma unroll
        for (int h = 0; h < 2; ++h) {
            #pragma unroll
            for (int ms = 0; ms < 4; ++ms) {
                const int row = wr + ms * 16 + laneN;
                av[h][ms] = *(const s16x8*)&As[row * 64 + ((h * 4 + quad) ^ (row & 7)) * 8];
            }
            #pragma unroll
            for (int ns = 0; ns < 4; ++ns) {
                const int row = wc + ns * 16 + laneN;
                bv[h][ns] = *(const s16x8*)&Bs[row * 64 + ((h * 4 + quad) ^ (row & 7)) * 8];
            }
        }
        if (it + 1 < KI) issueG((it + 1) << 6, buf ^ 1);  // overlap w/ MFMA
        #pragma unroll
        for (int ms = 0; ms < 4; ++ms)
            #pragma unroll
            for (int ns = 0; ns < 4; ++ns) {
                acc[ms][ns] = MFMA32(av[0][ms], bv[0][ns], acc[ms][ns]);
                acc[ms][ns] = MFMA32(av[1][ms], bv[1][ns], acc[ms][ns]);
            }
    }

    if (MODE == 0) {
        #pragma unroll
        for (int ms = 0; ms < 4; ++ms) {
            const int gm0 = rm0 + wr + ms * 16 + quad * 4;
            #pragma unroll
            for (int ns = 0; ns < 4; ++ns) {
                const int gn = rn0 + wc + ns * 16 + laneN;
                const float bb = bias[gn];
                #pragma unroll
                for (int r = 0; r < 4; ++r)
                    Cf[(size_t)(gm0 + r) * N + gn] = acc[ms][ns][r] + bb;
            }
        }
    } else {
        const int s = rn0 >> 10;                 // 0=Q 1=K 2=V, block-uniform
        const int bidx = rm0 >> 11, t0 = rm0 & (T_ - 1);
        if (s < 2) {
            const float fs = (s == 0) ? 0.125f * 1.44269504088896f : 1.0f;
            unsigned short* P = (s == 0) ? Qo : Ko;
            #pragma unroll
            for (int ms = 0; ms < 4; ++ms) {
                const int lm0 = wr + ms * 16 + quad * 4;
                #pragma unroll
                for (int ns = 0; ns < 4; ++ns) {
                    const int gn = rn0 + wc + ns * 16 + laneN;
                    const float bb = bias[gn];
                    const int rr = gn & 1023, hh = rr >> 6, dd = rr & 63;
                    const size_t base = ((size_t)(bidx * H_ + hh) * T_ + t0);
                    #pragma unroll
                    for (int r = 0; r < 4; ++r)
                        P[(base + lm0 + r) * HD_ + dd] =
                            f2bf((acc[ms][ns][r] + bb) * fs);
                }
            }
        } else {
            // V: acc -> swizzled LDS [n_local][m_local] -> coalesced stores
            __syncthreads();                     // all K-loop LDS reads done
            #pragma unroll
            for (int ms = 0; ms < 4; ++ms) {
                const int lm0 = wr + ms * 16 + quad * 4;
                #pragma unroll
                for (int ns = 0; ns < 4; ++ns) {
                    const int nl = wc + ns * 16 + laneN;
                    const float bb = bias[rn0 + nl];
                    const int sw = (nl & 7) << 3;
                    #pragma unroll
                    for (int r = 0; r < 4; ++r)
                        SMEM[nl * 128 + ((lm0 + r) ^ sw)] =
                            f2bf(acc[ms][ns][r] + bb);
                }
            }
            __syncthreads();
            const int nl = tid >> 1, half = tid & 1;
            const int hh = nl >> 6, d = nl & 63;
            const int hAbs = bidx * H_ + ((rn0 & 1023) >> 6) + hh;
            unsigned short* rowp = Vo + ((size_t)hAbs * HD_ + d) * T_ + t0;
            const int swz = nl & 7;
            #pragma unroll
            for (int j = 0; j < 8; ++j) {
                const s16x8 vv = *(const s16x8*)&SMEM[nl * 128 + half * 64 + j * 8];
                const int mlog = half * 64 + ((j ^ swz) * 8);
                *(s16x8*)(rowp + mlog) = vv;
            }
        }
    }
}

// ---------------- flash attention v6 (proven 64-key tiles) ----------------
// grid(B*H, T/256), 512 thr (8 waves), 32 q-rows/wave, 256 q-rows/block.
// All q-blocks of one head land on one XCD -> K/V stay L2-resident.
// 8 waves share each staged K/V tile.  Fixed-max base-2 softmax; mask bias
// enters as the MFMA ACCUMULATOR INIT; exp is raw v_exp_f32.  S^T computed
// with PERMUTED K-rows so its C-layout concatenates into the 16x16x32
// A-operand -> PV and row-sum (B=ones) run as MFMA32 straight from
// registers.  K/V double-buffered in LDS via global_load_lds, XOR-swizzled;
// one barrier/tile.
__global__ __launch_bounds__(512, 4)
void attn_kernel(const unsigned short* __restrict__ Q,
                 const unsigned short* __restrict__ Kb,
                 const unsigned short* __restrict__ VT,
                 const int* __restrict__ mask,
                 unsigned short* __restrict__ Out) {
    __shared__ __align__(16) unsigned short Ks[2][64 * 64];  // [key][d] swizzled
    __shared__ __align__(16) unsigned short Vs[2][64 * 64];  // [d][key] swizzled
    __shared__ float biasF[T_];                              // fp32 mask bias
    const int tid = threadIdx.x;
    const int lane = tid & 63;
    const int w = tid >> 6;                                  // 0..7
    const int laneN = lane & 15, quad = lane >> 4;
    const int x7 = laneN & 7;
    const int bh = blockIdx.x;
    const int b = bh >> 4, h = bh & 15;
    const int qbase = blockIdx.y * 256 + w * 32;

    for (int i = tid; i < T_; i += 512)
        biasF[i] = mask[b * T_ + i] ? 0.f : -1.0e9f;

    // Q B-operand frags (pre-scaled by 0.125*log2e in GEMM1 epilogue)
    s16x8 qf[2][2];
    #pragma unroll
    for (int qg = 0; qg < 2; ++qg) {
        const size_t qoff = ((size_t)bh * T_ + qbase + qg * 16 + laneN) * HD_ + quad * 8;
        qf[qg][0] = *(const s16x8*)&Q[qoff];
        qf[qg][1] = *(const s16x8*)&Q[qoff + 32];
    }

    s16x8 ones;
    #pragma unroll
    for (int j = 0; j < 8; ++j) ones[j] = (short)0x3F80;   // bf16 1.0

    const size_t kRow0 = (size_t)bh * T_ * HD_;
    const size_t vRow0 = (size_t)bh * HD_ * T_;

    // K swizzle f(row) = (row&3) | (((row>>3)&1)<<2); V swizzle f(d) = d&7
    // 512 threads -> exactly one K chunk + one V chunk per thread per tile.
    auto issueTile = [&](int kt, int bufsel) {
        const int kbase = kt * 64;
        {
            const int c = tid;                              // 512 K chunks
            const int row = c >> 3, s = c & 7;
            const int fk = (row & 3) | (((row >> 3) & 1) << 2);
            const int g = s ^ fk;
            async16(Kb + kRow0 + (size_t)(kbase + row) * HD_ + g * 8,
                    &Ks[bufsel][c * 8]);
        }
        {
            const int c = tid;                              // 512 V chunks
            const int d = c >> 3, s = c & 7, g = s ^ (d & 7);
            async16(VT + vRow0 + (size_t)d * T_ + kbase + g * 8,
                    &Vs[bufsel][c * 8]);
        }
    };

    issueTile(0, 0);

    f32x4 O[2][4] = {};        // [qg][nt]; lane: q=quad*4+r, d=nt*16+laneN
    f32x4 liacc[2] = {};       // [qg]; lane: q=quad*4+r (row-sums via MFMA)

    // permuted K rows: rowA(laneN) covers keys quad*8+r after MFMA
    const int rowA = ((laneN >> 2) << 3) + (laneN & 3);     // +4 -> twin half

    #pragma unroll 2
    for (int kt = 0; kt < T_ / 64; ++kt) {
        const int buf = kt & 1;
        const int kbase = kt * 64;
        __syncthreads();                       // buf ready; buf^1 free
        if (kt + 1 < T_ / 64) issueTile(kt + 1, buf ^ 1);

        s16x8 pf[2][2];        // [qg][g32] A-operand P frags (k=quad*8+j)
        #pragma unroll
        for (int g32 = 0; g32 < 2; ++g32) {
            // K frags at permuted rows; slot = chunk ^ x7 (2-way, free)
            const int ra = g32 * 32 + rowA;
            const s16x8 kA0 = *(const s16x8*)&Ks[buf][(ra * 8 + (quad ^ x7)) * 8];
            const s16x8 kA1 = *(const s16x8*)&Ks[buf][(ra * 8 + ((4 + quad) ^ x7)) * 8];
            const s16x8 kB0 = *(const s16x8*)&Ks[buf][((ra + 4) * 8 + (quad ^ x7)) * 8];
            const s16x8 kB1 = *(const s16x8*)&Ks[buf][((ra + 4) * 8 + ((4 + quad) ^ x7)) * 8];
            // bias for keys g32*32 + quad*8 + (0..7) -> MFMA acc init
            const f32x4 bA = *(const f32x4*)&biasF[kbase + g32 * 32 + quad * 8];
            const f32x4 bB = *(const f32x4*)&biasF[kbase + g32 * 32 + quad * 8 + 4];
            #pragma unroll
            for (int qg = 0; qg < 2; ++qg) {
                f32x4 Sa = bA, Sb = bB;        // bias as accumulator init
                Sa = MFMA32(kA0, qf[qg][0], Sa);
                Sa = MFMA32(kA1, qf[qg][1], Sa);
                Sb = MFMA32(kB0, qf[qg][0], Sb);
                Sb = MFMA32(kB1, qf[qg][1], Sb);
                // fixed-max softmax: P = exp2(S)  (raw v_exp_f32)
                #pragma unroll
                for (int r = 0; r < 4; ++r) {
                    Sa[r] = FEXP2(Sa[r]);
                    Sb[r] = FEXP2(Sb[r]);
                }
                union { s16x8 v; unsigned int u[4]; } pu;
                pu.u[0] = pkbf(Sa[0], Sa[1]);
                pu.u[1] = pkbf(Sa[2], Sa[3]);
                pu.u[2] = pkbf(Sb[0], Sb[1]);
                pu.u[3] = pkbf(Sb[2], Sb[3]);
                pf[qg][g32] = pu.v;
            }
        }

        // ---- O += P @ V ; li += P @ 1 (all MFMA32, P from registers) ----
        #pragma unroll
        for (int g32 = 0; g32 < 2; ++g32) {
            s16x8 vf[4];
            #pragma unroll
            for (int nt = 0; nt < 4; ++nt) {
                const int d = nt * 16 + laneN;
                vf[nt] = *(const s16x8*)&Vs[buf][(d * 8 + ((g32 * 4 + quad) ^ x7)) * 8];
            }
            #pragma unroll
            for (int qg = 0; qg < 2; ++qg) {
                #pragma unroll
                for (int nt = 0; nt < 4; ++nt)
                    O[qg][nt] = MFMA32(pf[qg][g32], vf[nt], O[qg][nt]);
                liacc[qg] = MFMA32(pf[qg][g32], ones, liacc[qg]);
            }
        }
    }

    // ---- epilogue: Out[b,t, h*64+d] bf16 ; li already in O's layout ----
    #pragma unroll
    for (int qg = 0; qg < 2; ++qg) {
        #pragma unroll
        for (int r = 0; r < 4; ++r) {
            const float inv = 1.0f / liacc[qg][r];
            const int tq = qbase + qg * 16 + quad * 4 + r;
            #pragma unroll
            for (int nt = 0; nt < 4; ++nt)
                Out[(size_t)(b * T_ + tq) * D_ + h * HD_ + nt * 16 + laneN] =
                    f2bf(O[qg][nt][r] * inv);
        }
    }
}

extern "C" void kernel_launch(void* const* d_in, const int* in_sizes, int n_in,
                              void* d_out, int out_size, void* d_ws, size_t ws_size,
                              hipStream_t stream) {
    const float* x     = (const float*)d_in[0];
    const int*   mask  = (const int*)d_in[1];
    const float* W_qkv = (const float*)d_in[2];
    const float* b_qkv = (const float*)d_in[3];
    const float* W_out = (const float*)d_in[4];
    const float* b_out = (const float*)d_in[5];
    float* out = (float*)d_out;

    unsigned short* ws = (unsigned short*)d_ws;
    const size_t NX = (size_t)B_ * T_ * D_;          // 8388608
    unsigned short* xb  = ws;                        // x bf16; reused for attn out
    unsigned short* Qb  = xb + NX;
    unsigned short* Kb  = Qb + NX;
    unsigned short* Vtb = Kb + NX;
    unsigned short* Wqt = Vtb + NX;                  // [3D, D]
    unsigned short* Wot = Wqt + (size_t)3 * D_ * D_; // [D, D]
    unsigned short* attn = xb;                       // alias: xb dead after GEMM1

    prep_kernel<<<12288, 256, 0, stream>>>(x, xb, W_qkv, Wqt, W_out, Wot);
    gemm_bt_kernel<1><<<dim3(B_ * T_ / 128, 3 * D_ / 128), 256, 0, stream>>>(
        xb, Wqt, b_qkv, nullptr, Qb, Kb, Vtb, B_ * T_, 3 * D_, D_);
    attn_kernel<<<dim3(B_ * H_, T_ / 256), 512, 0, stream>>>(Qb, Kb, Vtb, mask, attn);
    gemm_bt_kernel<0><<<dim3(B_ * T_ / 128, D_ / 128), 256, 0, stream>>>(
        attn, Wot, b_out, out, nullptr, nullptr, nullptr, B_ * T_, D_, D_);
}